// Round 2
// baseline (3192.237 us; speedup 1.0000x reference)
//
#include <hip/hip_runtime.h>
#include <math.h>

#define CDIM 256
#define HD 8
#define DD 32
#define TM 64
#define TN 64
#define BK 16
#define NT 3
#define ET 5
#define EB 64

// ---------------- node-type buckets ----------------
__global__ void count_ntype_k(const int* __restrict__ ntype, int N, int* __restrict__ cnt) {
    int i = blockIdx.x * 256 + threadIdx.x;
    int t = (i < N) ? ntype[i] : -1;
#pragma unroll
    for (int r = 0; r < NT; ++r) {
        unsigned long long m = __ballot(t == r);
        if ((threadIdx.x & 63) == 0 && m) atomicAdd(&cnt[r], __popcll(m));
    }
}

__global__ void scan3_k(const int* __restrict__ cnt, int* __restrict__ off, int* __restrict__ cur) {
    if (threadIdx.x == 0) {
        off[0] = 0;
        off[1] = cnt[0];
        off[2] = cnt[0] + cnt[1];
        off[3] = cnt[0] + cnt[1] + cnt[2];
        cur[0] = 0; cur[1] = off[1]; cur[2] = off[2];
    }
}

__global__ void scatter_perm_k(const int* __restrict__ ntype, int N, int* __restrict__ cur,
                               int* __restrict__ perm) {
    int i = blockIdx.x * 256 + threadIdx.x;
    if (i < N) {
        int t = ntype[i];
        int p = atomicAdd(&cur[t], 1);
        perm[p] = i;
    }
}

// ---------------- edge counting sort by (etype, dst) ----------------
__global__ void ehist_k(const int* __restrict__ dst, const int* __restrict__ etype, int E, int N,
                        int* __restrict__ khist, int* __restrict__ ethist) {
    int i = blockIdx.x * 256 + threadIdx.x;
    int et = -1;
    if (i < E) {
        et = etype[i];
        atomicAdd(&khist[et * N + dst[i]], 1);
    }
#pragma unroll
    for (int r = 0; r < ET; ++r) {
        unsigned long long m = __ballot(et == r);
        if ((threadIdx.x & 63) == 0 && m) atomicAdd(&ethist[r], __popcll(m));
    }
}

__global__ void kscan1_k(const int* __restrict__ khist, int* __restrict__ kscan,
                         int* __restrict__ bsum, int KEYS) {
    __shared__ int s[256];
    int b = blockIdx.x, t = threadIdx.x, i = b * 256 + t;
    int v = (i < KEYS) ? khist[i] : 0;
    s[t] = v; __syncthreads();
    for (int o = 1; o < 256; o <<= 1) {
        int u = (t >= o) ? s[t - o] : 0; __syncthreads();
        s[t] += u; __syncthreads();
    }
    if (i < KEYS) kscan[i] = s[t] - v;
    if (t == 255) bsum[b] = s[t];
}

__global__ void kscan2_k(int* __restrict__ bsum, int NB) {
    __shared__ int s[1024];
    int t = threadIdx.x;
    int v = (t < NB) ? bsum[t] : 0;
    s[t] = v; __syncthreads();
    for (int o = 1; o < 1024; o <<= 1) {
        int u = (t >= o) ? s[t - o] : 0; __syncthreads();
        s[t] += u; __syncthreads();
    }
    if (t < NB) bsum[t] = s[t] - v;
}

__global__ void kscan3_k(int* __restrict__ kscan, const int* __restrict__ bsum, int KEYS) {
    int i = blockIdx.x * 256 + threadIdx.x;
    if (i < KEYS) kscan[i] += bsum[blockIdx.x];
}

__global__ void etmeta_k(const int* __restrict__ ethist, int* __restrict__ prevedges,
                         int* __restrict__ etbase) {
    if (threadIdx.x == 0) {
        int pe = 0, eb = 0;
        for (int r = 0; r < ET; ++r) {
            prevedges[r] = pe; etbase[r] = eb;
            pe += ethist[r];
            eb += (ethist[r] + 63) & ~63;
        }
    }
}

__global__ void escatter_k(const int* __restrict__ dst, const int* __restrict__ etype, int E, int N,
                           int* __restrict__ kscan, const int* __restrict__ prevedges,
                           const int* __restrict__ etbase, int* __restrict__ eperm) {
    int e = blockIdx.x * 256 + threadIdx.x;
    if (e < E) {
        int et = etype[e];
        int key = et * N + dst[e];
        int pos = etbase[et] - prevedges[et] + atomicAdd(&kscan[key], 1);
        eperm[pos] = e;
    }
}

// ---------------- typed GEMM (type-uniform blocks via perm buckets) ----------------
template<bool FINAL>
__global__ __launch_bounds__(256) void gemm_typed_k(
    const float* __restrict__ A, const float* __restrict__ W,
    float* __restrict__ out,
    const int* __restrict__ perm, const int* __restrict__ off,
    int N, int bpt,
    const float* __restrict__ denom, const float* __restrict__ x,
    const float* __restrict__ skip)
{
    __shared__ float As[BK][TM + 4];
    __shared__ float Bs[BK][TN];

    int t  = blockIdx.x / bpt;
    int bi = blockIdx.x % bpt;
    int i0 = off[t] + bi * TM;
    int iend = off[t + 1];
    if (i0 >= iend) return;

    int tid  = threadIdx.x;
    int col0 = blockIdx.y * TN;

    int srow = tid >> 2;
    int sc4  = (tid & 3) * 4;
    int gsrow = (i0 + srow < iend) ? perm[i0 + srow] : -1;

    int tr = tid >> 4;
    int tc = tid & 15;
    int prow[4];
#pragma unroll
    for (int i = 0; i < 4; i++) {
        int idx = i0 + tr * 4 + i;
        prow[i] = (idx < iend) ? perm[idx] : -1;
    }

    float acc[4][4] = {};
    const float* Wt = W + (size_t)t * CDIM * CDIM;

    auto loadA = [&](int k0) -> float4 {
        float4 av = make_float4(0.f, 0.f, 0.f, 0.f);
        if (gsrow >= 0) {
            av = *(const float4*)(A + (size_t)gsrow * CDIM + k0 + sc4);
            if (FINAL) {
                float dn = denom[gsrow * HD + ((k0 + sc4) >> 5)];
                float s = dn > 0.f ? 1.0f / dn : 0.f;
                av.x *= s; av.y *= s; av.z *= s; av.w *= s;
            }
        }
        return av;
    };
    auto loadB = [&](int k0) -> float4 {
        return *(const float4*)(Wt + (size_t)(k0 + (tid >> 4)) * CDIM + col0 + (tid & 15) * 4);
    };

    float4 av = loadA(0);
    float4 bv = loadB(0);

    for (int k0 = 0; k0 < CDIM; k0 += BK) {
        __syncthreads();
        As[sc4 + 0][srow] = av.x;
        As[sc4 + 1][srow] = av.y;
        As[sc4 + 2][srow] = av.z;
        As[sc4 + 3][srow] = av.w;
        *(float4*)&Bs[tid >> 4][(tid & 15) * 4] = bv;
        __syncthreads();

        if (k0 + BK < CDIM) {          // prefetch next tile; overlaps FMA loop below
            av = loadA(k0 + BK);
            bv = loadB(k0 + BK);
        }

#pragma unroll
        for (int kk = 0; kk < BK; kk++) {
            float4 a = *(const float4*)&As[kk][tr * 4];
            float4 b = *(const float4*)&Bs[kk][tc * 4];
            acc[0][0] += a.x * b.x; acc[0][1] += a.x * b.y; acc[0][2] += a.x * b.z; acc[0][3] += a.x * b.w;
            acc[1][0] += a.y * b.x; acc[1][1] += a.y * b.y; acc[1][2] += a.y * b.z; acc[1][3] += a.y * b.w;
            acc[2][0] += a.z * b.x; acc[2][1] += a.z * b.y; acc[2][2] += a.z * b.z; acc[2][3] += a.z * b.w;
            acc[3][0] += a.w * b.x; acc[3][1] += a.w * b.y; acc[3][2] += a.w * b.z; acc[3][3] += a.w * b.w;
        }
    }

    float alpha = 0.f, beta = 0.f;
    if (FINAL) {
        alpha = 1.f / (1.f + __expf(-skip[t]));
        beta = 1.f - alpha;
    }

#pragma unroll
    for (int i = 0; i < 4; i++) {
        int row = prow[i];
        if (row < 0) continue;
        size_t base = (size_t)row * CDIM + col0 + tc * 4;
        float4 r = make_float4(acc[i][0], acc[i][1], acc[i][2], acc[i][3]);
        if (FINAL) {
            float4 xv = *(const float4*)(x + base);
            r.x = r.x * alpha + xv.x * beta;
            r.y = r.y * alpha + xv.y * beta;
            r.z = r.z * alpha + xv.z * beta;
            r.w = r.w * alpha + xv.w * beta;
        }
        *(float4*)(out + base) = r;
    }
}

// ---------------- edge kernel (etype-uniform, dst-sorted blocks) ----------------
__global__ __launch_bounds__(256) void edge_k(
    const float* __restrict__ kbuf, const float* __restrict__ qbuf, const float* __restrict__ vbuf,
    const float* __restrict__ Ratt, const float* __restrict__ Rmsg, const float* __restrict__ pri,
    const int* __restrict__ src, const int* __restrict__ dst, const int* __restrict__ etype,
    const int* __restrict__ eperm,
    float* __restrict__ acc, float* __restrict__ denom)
{
    __shared__ float Ra[DD][DD];   // 4 KB
    __shared__ float Rm[DD][DD];   // 4 KB
    __shared__ int s_et;

    int tid = threadIdx.x;
    int el = tid >> 2;
    int qq = tid & 3;
    int base = blockIdx.x * EB;

    if (tid == 0) {
        int e0 = eperm[base];
        s_et = (e0 >= 0) ? etype[e0] : -1;
    }
    __syncthreads();
    int et = s_et;
    if (et < 0) return;               // fully-padded block (uniform exit)

    int e = eperm[base + el];
    bool valid = e >= 0;
    int s = 0, d_ = 0;
    if (valid) { s = src[e]; d_ = dst[e]; }

    const float rsD = 0.17677669529663687f;  // 1/sqrt(32)

    for (int h = 0; h < HD; ++h) {
        __syncthreads();
        // stage this etype's relation matrices for head h: 1024 floats each
        ((float4*)&Ra[0][0])[tid] = ((const float4*)(Ratt + ((size_t)(et * HD + h)) * (DD * DD)))[tid];
        ((float4*)&Rm[0][0])[tid] = ((const float4*)(Rmsg + ((size_t)(et * HD + h)) * (DD * DD)))[tid];
        __syncthreads();
        if (!valid) continue;

        const float* kp = kbuf + (size_t)s  * CDIM + h * DD + qq * 8;
        const float* qp = qbuf + (size_t)d_ * CDIM + h * DD + qq * 8;
        const float* vp = vbuf + (size_t)s  * CDIM + h * DD + qq * 8;
        float4 k0 = *(const float4*)kp,  k1 = *(const float4*)(kp + 4);
        float4 q0 = *(const float4*)qp,  q1 = *(const float4*)(qp + 4);
        float4 v0 = *(const float4*)vp,  v1 = *(const float4*)(vp + 4);
        float kreg[8] = {k0.x, k0.y, k0.z, k0.w, k1.x, k1.y, k1.z, k1.w};
        float qreg[8] = {q0.x, q0.y, q0.z, q0.w, q1.x, q1.y, q1.z, q1.w};
        float vreg[8] = {v0.x, v0.y, v0.z, v0.w, v1.x, v1.y, v1.z, v1.w};

        float kw[8] = {};
        float mv[8] = {};
#pragma unroll
        for (int dd = 0; dd < DD; ++dd) {
            float kd = __shfl(kreg[dd & 7], dd >> 3, 4);
            float vd = __shfl(vreg[dd & 7], dd >> 3, 4);
            const float* rr = &Ra[dd][qq * 8];
            const float* rm = &Rm[dd][qq * 8];
#pragma unroll
            for (int j = 0; j < 8; ++j) {
                kw[j] += kd * rr[j];
                mv[j] += vd * rm[j];
            }
        }
        float adot = 0.f;
#pragma unroll
        for (int j = 0; j < 8; ++j) adot += kw[j] * qreg[j];
        adot += __shfl_xor(adot, 1, 4);
        adot += __shfl_xor(adot, 2, 4);
        float ex = __expf(adot * pri[et * HD + h] * rsD);

        float* ap = acc + (size_t)d_ * CDIM + h * DD + qq * 8;
#pragma unroll
        for (int j = 0; j < 8; ++j) atomicAdd(ap + j, mv[j] * ex);
        if (qq == 0) atomicAdd(denom + (size_t)d_ * HD + h, ex);
    }
}

// ---------------- launch ----------------
extern "C" void kernel_launch(void* const* d_in, const int* in_sizes, int n_in,
                              void* d_out, int out_size, void* d_ws, size_t ws_size,
                              hipStream_t stream) {
    const float* x    = (const float*)d_in[0];
    const float* Wk   = (const float*)d_in[1];
    const float* Wq   = (const float*)d_in[2];
    const float* Wv   = (const float*)d_in[3];
    const float* Ratt = (const float*)d_in[4];
    const float* Rmsg = (const float*)d_in[5];
    const float* pri  = (const float*)d_in[6];
    const float* Wa   = (const float*)d_in[7];
    const float* skip = (const float*)d_in[8];
    const int* src   = (const int*)d_in[9];
    const int* dst   = (const int*)d_in[10];
    const int* etype = (const int*)d_in[11];
    const int* ntype = (const int*)d_in[12];

    int N = in_sizes[12];
    int E = in_sizes[9];
    const size_t NC = (size_t)N * CDIM;
    const int KEYS = ET * N;
    const int NB = (KEYS + 255) / 256;          // scan blocks (977 for N=50000)
    const int EPAD = E + ET * 64 + 64;

    // ---- workspace layout ----
    float* ws   = (float*)d_ws;
    float* accb = ws;                            // NC
    float* denb = accb + NC;                     // N*HD
    int* cnt    = (int*)(denb + (size_t)N * HD); // 4
    int* off    = cnt + 4;                       // 4
    int* cur    = off + 4;                       // 4
    int* khist  = cur + 4;                       // KEYS
    int* ethist = khist + KEYS;                  // 8
    // ---- end of zeroed region ----
    int* kscan  = ethist + 8;                    // KEYS
    int* bsum   = kscan + KEYS;                  // 1024
    int* prevedges = bsum + 1024;                // 8
    int* etbase = prevedges + 8;                 // 8
    int* perm   = etbase + 8;                    // N
    int* eperm  = perm + N;                      // EPAD
    float* kb   = (float*)(eperm + EPAD);        // NC
    float* qb   = kb + NC;                       // NC
    float* vb   = qb + NC;                       // NC

    size_t zero_ints = NC + (size_t)N * HD + 12 + KEYS + 8;
    hipMemsetAsync(accb, 0, zero_ints * sizeof(int), stream);
    hipMemsetAsync(eperm, 0xFF, (size_t)EPAD * sizeof(int), stream);

    // node buckets
    count_ntype_k<<<(N + 255) / 256, 256, 0, stream>>>(ntype, N, cnt);
    scan3_k<<<1, 64, 0, stream>>>(cnt, off, cur);
    scatter_perm_k<<<(N + 255) / 256, 256, 0, stream>>>(ntype, N, cur, perm);

    // edge (etype,dst) counting sort
    ehist_k<<<(E + 255) / 256, 256, 0, stream>>>(dst, etype, E, N, khist, ethist);
    kscan1_k<<<NB, 256, 0, stream>>>(khist, kscan, bsum, KEYS);
    kscan2_k<<<1, 1024, 0, stream>>>(bsum, NB);
    kscan3_k<<<NB, 256, 0, stream>>>(kscan, bsum, KEYS);
    etmeta_k<<<1, 64, 0, stream>>>(ethist, prevedges, etbase);
    escatter_k<<<(E + 255) / 256, 256, 0, stream>>>(dst, etype, E, N, kscan, prevedges, etbase, eperm);

    // k/q/v projections
    int bpt = (N + TM - 1) / TM;
    dim3 gg(NT * bpt, CDIM / TN);
    gemm_typed_k<false><<<gg, 256, 0, stream>>>(x, Wk, kb, perm, off, N, bpt, nullptr, nullptr, nullptr);
    gemm_typed_k<false><<<gg, 256, 0, stream>>>(x, Wq, qb, perm, off, N, bpt, nullptr, nullptr, nullptr);
    gemm_typed_k<false><<<gg, 256, 0, stream>>>(x, Wv, vb, perm, off, N, bpt, nullptr, nullptr, nullptr);

    // edge pass
    int eblocks = (E + ET * 64 + 63) / 64;
    edge_k<<<eblocks, 256, 0, stream>>>(kb, qb, vb, Ratt, Rmsg, pri, src, dst, etype, eperm,
                                        accb, denb);

    // output projection + gated skip
    gemm_typed_k<true><<<gg, 256, 0, stream>>>(accb, Wa, (float*)d_out, perm, off, N, bpt,
                                               denb, x, skip);
}

// Round 4
// 1258.610 us; speedup vs baseline: 2.5363x; 2.5363x over previous
//
#include <hip/hip_runtime.h>
#include <math.h>

#define CDIM 256
#define HD 8
#define DD 32
#define TM 64
#define TN 64
#define BK 16
#define NT 3
#define ET 5

typedef unsigned short u16;
__device__ __forceinline__ float b2f(u16 u) { return __uint_as_float(((unsigned)u) << 16); }
__device__ __forceinline__ u16 f2b(float x) {
    unsigned u = __float_as_uint(x);
    return (u16)((u + 0x7FFF + ((u >> 16) & 1)) >> 16);
}

// ---------------- node-type buckets ----------------
__global__ void count_ntype_k(const int* __restrict__ ntype, int N, int* __restrict__ cnt) {
    int i = blockIdx.x * 256 + threadIdx.x;
    int t = (i < N) ? ntype[i] : -1;
#pragma unroll
    for (int r = 0; r < NT; ++r) {
        unsigned long long m = __ballot(t == r);
        if ((threadIdx.x & 63) == 0 && m) atomicAdd(&cnt[r], __popcll(m));
    }
}

__global__ void scan3_k(const int* __restrict__ cnt, int* __restrict__ off, int* __restrict__ cur) {
    if (threadIdx.x == 0) {
        off[0] = 0;
        off[1] = cnt[0];
        off[2] = cnt[0] + cnt[1];
        off[3] = cnt[0] + cnt[1] + cnt[2];
        cur[0] = 0; cur[1] = off[1]; cur[2] = off[2];
    }
}

__global__ void scatter_perm_k(const int* __restrict__ ntype, int N, int* __restrict__ cur,
                               int* __restrict__ perm) {
    int i = blockIdx.x * 256 + threadIdx.x;
    if (i < N) {
        int t = ntype[i];
        int p = atomicAdd(&cur[t], 1);
        perm[p] = i;
    }
}

// ---------------- edge counting sort by key = dst*ET + etype ----------------
__global__ void ehist_k(const int* __restrict__ dst, const int* __restrict__ etype, int E,
                        int* __restrict__ khist) {
    int i = blockIdx.x * 256 + threadIdx.x;
    if (i < E) atomicAdd(&khist[dst[i] * ET + etype[i]], 1);
}

__global__ void kscan1_k(const int* __restrict__ khist, int* __restrict__ kscan,
                         int* __restrict__ bsum, int KEYS) {
    __shared__ int s[256];
    int b = blockIdx.x, t = threadIdx.x, i = b * 256 + t;
    int v = (i < KEYS) ? khist[i] : 0;
    s[t] = v; __syncthreads();
    for (int o = 1; o < 256; o <<= 1) {
        int u = (t >= o) ? s[t - o] : 0; __syncthreads();
        s[t] += u; __syncthreads();
    }
    if (i < KEYS) kscan[i] = s[t] - v;
    if (t == 255) bsum[b] = s[t];
}

__global__ void kscan2_k(int* __restrict__ bsum, int NB) {
    __shared__ int s[1024];
    int t = threadIdx.x;
    int v = (t < NB) ? bsum[t] : 0;
    s[t] = v; __syncthreads();
    for (int o = 1; o < 1024; o <<= 1) {
        int u = (t >= o) ? s[t - o] : 0; __syncthreads();
        s[t] += u; __syncthreads();
    }
    if (t < NB) bsum[t] = s[t] - v;
}

__global__ void kscan3_k(int* __restrict__ kscan, const int* __restrict__ bsum, int KEYS) {
    int i = blockIdx.x * 256 + threadIdx.x;
    if (i < KEYS) kscan[i] += bsum[blockIdx.x];
}

__global__ void rowptr_k(const int* __restrict__ kscan, int* __restrict__ rowptr, int KEYS, int E) {
    int i = blockIdx.x * 256 + threadIdx.x;
    if (i < KEYS) rowptr[i] = kscan[i];
    if (i == KEYS) rowptr[KEYS] = E;
}

__global__ void escatter_k(const int* __restrict__ src, const int* __restrict__ dst,
                           const int* __restrict__ etype, int E,
                           int* __restrict__ kscan, int* __restrict__ epay) {
    int e = blockIdx.x * 256 + threadIdx.x;
    if (e < E) {
        int pos = atomicAdd(&kscan[dst[e] * ET + etype[e]], 1);
        epay[pos] = src[e];
    }
}

// ---------------- typed GEMM ----------------
// MODE 0: out = bf16 buffer (k/q/v projections). MODE 1: final f32 out with denom scale + skip blend.
template<int MODE>
__global__ __launch_bounds__(256) void gemm_typed_k(
    const float* __restrict__ A, const float* __restrict__ W, void* __restrict__ outv,
    const int* __restrict__ perm, const int* __restrict__ off,
    int N, int bpt,
    const float* __restrict__ denom, const float* __restrict__ x,
    const float* __restrict__ skip)
{
    __shared__ float As[BK][TM + 4];
    __shared__ float Bs[BK][TN];

    int t  = blockIdx.x / bpt;
    int bi = blockIdx.x % bpt;
    int i0 = off[t] + bi * TM;
    int iend = off[t + 1];
    if (i0 >= iend) return;

    int tid  = threadIdx.x;
    int col0 = blockIdx.y * TN;

    int srow = tid >> 2;
    int sc4  = (tid & 3) * 4;
    int gsrow = (i0 + srow < iend) ? perm[i0 + srow] : -1;

    int tr = tid >> 4;
    int tc = tid & 15;
    int prow[4];
#pragma unroll
    for (int i = 0; i < 4; i++) {
        int idx = i0 + tr * 4 + i;
        prow[i] = (idx < iend) ? perm[idx] : -1;
    }

    float acc[4][4] = {};
    const float* Wt = W + (size_t)t * CDIM * CDIM;

    auto loadA = [&](int k0) -> float4 {
        float4 av = make_float4(0.f, 0.f, 0.f, 0.f);
        if (gsrow >= 0) {
            av = *(const float4*)(A + (size_t)gsrow * CDIM + k0 + sc4);
            if (MODE == 1) {
                float dn = denom[gsrow * HD + ((k0 + sc4) >> 5)];
                float s = dn > 0.f ? 1.0f / dn : 0.f;
                av.x *= s; av.y *= s; av.z *= s; av.w *= s;
            }
        }
        return av;
    };
    auto loadB = [&](int k0) -> float4 {
        return *(const float4*)(Wt + (size_t)(k0 + (tid >> 4)) * CDIM + col0 + (tid & 15) * 4);
    };

    float4 av = loadA(0);
    float4 bv = loadB(0);

    for (int k0 = 0; k0 < CDIM; k0 += BK) {
        __syncthreads();
        As[sc4 + 0][srow] = av.x;
        As[sc4 + 1][srow] = av.y;
        As[sc4 + 2][srow] = av.z;
        As[sc4 + 3][srow] = av.w;
        *(float4*)&Bs[tid >> 4][(tid & 15) * 4] = bv;
        __syncthreads();

        if (k0 + BK < CDIM) {
            av = loadA(k0 + BK);
            bv = loadB(k0 + BK);
        }

#pragma unroll
        for (int kk = 0; kk < BK; kk++) {
            float4 a = *(const float4*)&As[kk][tr * 4];
            float4 b = *(const float4*)&Bs[kk][tc * 4];
            acc[0][0] += a.x * b.x; acc[0][1] += a.x * b.y; acc[0][2] += a.x * b.z; acc[0][3] += a.x * b.w;
            acc[1][0] += a.y * b.x; acc[1][1] += a.y * b.y; acc[1][2] += a.y * b.z; acc[1][3] += a.y * b.w;
            acc[2][0] += a.z * b.x; acc[2][1] += a.z * b.y; acc[2][2] += a.z * b.z; acc[2][3] += a.z * b.w;
            acc[3][0] += a.w * b.x; acc[3][1] += a.w * b.y; acc[3][2] += a.w * b.z; acc[3][3] += a.w * b.w;
        }
    }

    if (MODE == 1) {
        float alpha = 1.f / (1.f + __expf(-skip[t]));
        float beta = 1.f - alpha;
        float* out = (float*)outv;
#pragma unroll
        for (int i = 0; i < 4; i++) {
            int row = prow[i];
            if (row < 0) continue;
            size_t base = (size_t)row * CDIM + col0 + tc * 4;
            float4 xv = *(const float4*)(x + base);
            float4 r;
            r.x = acc[i][0] * alpha + xv.x * beta;
            r.y = acc[i][1] * alpha + xv.y * beta;
            r.z = acc[i][2] * alpha + xv.z * beta;
            r.w = acc[i][3] * alpha + xv.w * beta;
            *(float4*)(out + base) = r;
        }
    } else {
        u16* out = (u16*)outv;
#pragma unroll
        for (int i = 0; i < 4; i++) {
            int row = prow[i];
            if (row < 0) continue;
            size_t base = (size_t)row * CDIM + col0 + tc * 4;
            ushort4 r;
            r.x = f2b(acc[i][0]); r.y = f2b(acc[i][1]);
            r.z = f2b(acc[i][2]); r.w = f2b(acc[i][3]);
            *(ushort4*)(out + base) = r;
        }
    }
}

// ---------------- per-et dense q transform: qw[n,h,r] = sum_c Ratt[et,h,r,c] * q[n,h,c] ----------------
__global__ __launch_bounds__(256) void relq_k(
    const u16* __restrict__ qb, const float* __restrict__ Ratt,
    u16* __restrict__ qw, int N, int et)
{
    __shared__ float Rs[DD][DD];      // Rs[c][r] = Ratt[et][h][r][c]
    __shared__ float ts[64][DD + 1];

    int h = blockIdx.y;
    int n0 = blockIdx.x * 64;
    int tid = threadIdx.x;

    {
        const float* Rp = Ratt + ((size_t)(et * HD + h)) * (DD * DD);
        float4 rv = ((const float4*)Rp)[tid];
        int r = tid >> 3, c4 = (tid & 7) * 4;
        Rs[c4 + 0][r] = rv.x; Rs[c4 + 1][r] = rv.y;
        Rs[c4 + 2][r] = rv.z; Rs[c4 + 3][r] = rv.w;
    }
    {
        int r = tid >> 2, c8 = (tid & 3) * 8;
        int n = n0 + r;
        if (n < N) {
            const u16* ip = qb + (size_t)n * CDIM + h * DD + c8;
            ushort4 a = *(const ushort4*)ip;
            ushort4 b = *(const ushort4*)(ip + 4);
            ts[r][c8 + 0] = b2f(a.x); ts[r][c8 + 1] = b2f(a.y);
            ts[r][c8 + 2] = b2f(a.z); ts[r][c8 + 3] = b2f(a.w);
            ts[r][c8 + 4] = b2f(b.x); ts[r][c8 + 5] = b2f(b.y);
            ts[r][c8 + 6] = b2f(b.z); ts[r][c8 + 7] = b2f(b.w);
        } else {
#pragma unroll
            for (int m = 0; m < 8; ++m) ts[r][c8 + m] = 0.f;
        }
    }
    __syncthreads();

    int nl = tid >> 2, fq = tid & 3;
    int n = n0 + nl;
    float acc[8] = {};
#pragma unroll
    for (int c = 0; c < DD; ++c) {
        float xv = ts[nl][c];
#pragma unroll
        for (int jj = 0; jj < 8; ++jj)
            acc[jj] += xv * Rs[c][fq * 8 + jj];
    }
    if (n < N) {
        u16* op = qw + (size_t)n * CDIM + h * DD + fq * 8;
        ushort4 o0, o1;
        o0.x = f2b(acc[0]); o0.y = f2b(acc[1]); o0.z = f2b(acc[2]); o0.w = f2b(acc[3]);
        o1.x = f2b(acc[4]); o1.y = f2b(acc[5]); o1.z = f2b(acc[6]); o1.w = f2b(acc[7]);
        *(ushort4*)op = o0;
        *(ushort4*)(op + 4) = o1;
    }
}

// ---------------- per-et gather: one wave per dst, Rmsg applied in-register post-sum ----------------
// h_contrib[d] = (sum_e ex_e * v[src_e]) @ Rmsg[et]; acc[d] += contrib; den[d,h] += sum ex
__global__ __launch_bounds__(256) void gather_et_k(
    const u16* __restrict__ kb, const u16* __restrict__ vb, const u16* __restrict__ qw,
    const float* __restrict__ Rmsg, const float* __restrict__ pri,
    const int* __restrict__ rowptr, const int* __restrict__ epay,
    float* __restrict__ acc, float* __restrict__ den, int N, int et)
{
    // layout: Rm_s[h*1057 + f*33 + d] = Rmsg[et][h][f][d]  (<=2-way bank conflicts)
    __shared__ float Rm_s[HD * 1057];

    int tid = threadIdx.x;
    {
        const float* Rp = Rmsg + (size_t)et * HD * DD * DD;
        for (int i = tid; i < HD * DD * DD; i += 256) {
            int h = i >> 10, f = (i >> 5) & 31, d = i & 31;
            Rm_s[h * 1057 + f * 33 + d] = Rp[i];
        }
    }
    __syncthreads();

    int lane = tid & 63;
    int wv = tid >> 6;
    int h = lane >> 3, j = lane & 7;
    float prif = pri[et * HD + h] * 0.17677669529663687f;   // pri/sqrt(32)
    int dbase = blockIdx.x * 64 + wv * 16;

    for (int slot = 0; slot < 16; ++slot) {
        int d = dbase + slot;
        if (d >= N) break;
        int key = d * ET + et;
        int p0 = rowptr[key], p1 = rowptr[key + 1];
        if (p0 == p1) continue;

        ushort4 qwu = *(const ushort4*)(qw + (size_t)d * CDIM + lane * 4);
        float qf0 = b2f(qwu.x), qf1 = b2f(qwu.y), qf2 = b2f(qwu.z), qf3 = b2f(qwu.w);

        float Sv0 = 0.f, Sv1 = 0.f, Sv2 = 0.f, Sv3 = 0.f, dsum = 0.f;
        for (int p = p0; p < p1; ++p) {
            int s = epay[p];
            ushort4 ku = *(const ushort4*)(kb + (size_t)s * CDIM + lane * 4);
            float t = b2f(ku.x) * qf0 + b2f(ku.y) * qf1 + b2f(ku.z) * qf2 + b2f(ku.w) * qf3;
            t += __shfl_xor(t, 1, 8);
            t += __shfl_xor(t, 2, 8);
            t += __shfl_xor(t, 4, 8);
            float ex = __expf(t * prif);
            ushort4 vu = *(const ushort4*)(vb + (size_t)s * CDIM + lane * 4);
            Sv0 += ex * b2f(vu.x); Sv1 += ex * b2f(vu.y);
            Sv2 += ex * b2f(vu.z); Sv3 += ex * b2f(vu.w);
            dsum += ex;
        }

        // out[m] = sum_f Sv_head[f] * Rmsg[h][f][j*4+m]
        float o0 = 0.f, o1 = 0.f, o2 = 0.f, o3 = 0.f;
        const float* rb = &Rm_s[h * 1057 + j * 4];
#pragma unroll
        for (int f = 0; f < DD; ++f) {
            int srcl = h * 8 + (f >> 2);
            float sf;
            switch (f & 3) {
                case 0:  sf = __shfl(Sv0, srcl, 64); break;
                case 1:  sf = __shfl(Sv1, srcl, 64); break;
                case 2:  sf = __shfl(Sv2, srcl, 64); break;
                default: sf = __shfl(Sv3, srcl, 64); break;
            }
            o0 += sf * rb[f * 33 + 0];
            o1 += sf * rb[f * 33 + 1];
            o2 += sf * rb[f * 33 + 2];
            o3 += sf * rb[f * 33 + 3];
        }

        float* ap = acc + (size_t)d * CDIM + lane * 4;
        float4 av = *(float4*)ap;
        av.x += o0; av.y += o1; av.z += o2; av.w += o3;
        *(float4*)ap = av;
        if (j == 0) den[d * HD + h] += dsum;
    }
}

// ---------------- launch ----------------
extern "C" void kernel_launch(void* const* d_in, const int* in_sizes, int n_in,
                              void* d_out, int out_size, void* d_ws, size_t ws_size,
                              hipStream_t stream) {
    const float* x    = (const float*)d_in[0];
    const float* Wk   = (const float*)d_in[1];
    const float* Wq   = (const float*)d_in[2];
    const float* Wv   = (const float*)d_in[3];
    const float* Ratt = (const float*)d_in[4];
    const float* Rmsg = (const float*)d_in[5];
    const float* pri  = (const float*)d_in[6];
    const float* Wa   = (const float*)d_in[7];
    const float* skip = (const float*)d_in[8];
    const int* src   = (const int*)d_in[9];
    const int* dst   = (const int*)d_in[10];
    const int* etype = (const int*)d_in[11];
    const int* ntype = (const int*)d_in[12];

    int N = in_sizes[12];
    int E = in_sizes[9];
    const size_t NC = (size_t)N * CDIM;
    const int KEYS = N * ET;
    const int NB = (KEYS + 255) / 256;

    // ---- workspace (~160 MB total) ----
    float* accb = (float*)d_ws;                  // NC f32
    float* denb = accb + NC;                     // N*HD f32
    u16* kb = (u16*)(denb + (size_t)N * HD);     // NC bf16
    u16* qb = kb + NC;                           // NC bf16
    u16* vb = qb + NC;                           // NC bf16
    u16* qw = vb + NC;                           // NC bf16 (reused per et)
    int* cnt    = (int*)(qw + NC);               // 4
    int* off    = cnt + 4;                       // 4
    int* cur    = off + 4;                       // 4
    int* khist  = cur + 4;                       // KEYS (zeroed with cnt/off/cur)
    int* kscan  = khist + KEYS;                  // KEYS
    int* bsum   = kscan + KEYS;                  // 1024
    int* rowptr = bsum + 1024;                   // KEYS+1
    int* perm   = rowptr + KEYS + 1;             // N
    int* epay   = perm + N;                      // E

    hipMemsetAsync(accb, 0, (NC + (size_t)N * HD) * sizeof(float), stream);
    hipMemsetAsync(cnt, 0, (size_t)(12 + KEYS) * sizeof(int), stream);

    // node buckets
    count_ntype_k<<<(N + 255) / 256, 256, 0, stream>>>(ntype, N, cnt);
    scan3_k<<<1, 64, 0, stream>>>(cnt, off, cur);
    scatter_perm_k<<<(N + 255) / 256, 256, 0, stream>>>(ntype, N, cur, perm);

    // edge counting sort by (dst, etype) -> CSR over KEYS
    ehist_k<<<(E + 255) / 256, 256, 0, stream>>>(dst, etype, E, khist);
    kscan1_k<<<NB, 256, 0, stream>>>(khist, kscan, bsum, KEYS);
    kscan2_k<<<1, 1024, 0, stream>>>(bsum, NB);
    kscan3_k<<<NB, 256, 0, stream>>>(kscan, bsum, KEYS);
    rowptr_k<<<(KEYS + 256) / 256, 256, 0, stream>>>(kscan, rowptr, KEYS, E);
    escatter_k<<<(E + 255) / 256, 256, 0, stream>>>(src, dst, etype, E, kscan, epay);

    // k/q/v projections (bf16 out)
    int bpt = (N + TM - 1) / TM;
    dim3 gg(NT * bpt, CDIM / TN);
    gemm_typed_k<0><<<gg, 256, 0, stream>>>(x, Wk, kb, perm, off, N, bpt, nullptr, nullptr, nullptr);
    gemm_typed_k<0><<<gg, 256, 0, stream>>>(x, Wq, qb, perm, off, N, bpt, nullptr, nullptr, nullptr);
    gemm_typed_k<0><<<gg, 256, 0, stream>>>(x, Wv, vb, perm, off, N, bpt, nullptr, nullptr, nullptr);

    // per-etype: dense q transform + gather (serialized on stream -> no acc race)
    int gblocks = (N + 63) / 64;
    for (int et = 0; et < ET; ++et) {
        dim3 rg(gblocks, HD);
        relq_k<<<rg, 256, 0, stream>>>(qb, Ratt, qw, N, et);
        gather_et_k<<<gblocks, 256, 0, stream>>>(kb, vb, qw, Rmsg, pri, rowptr, epay,
                                                 accb, denb, N, et);
    }

    // output projection + gated skip
    gemm_typed_k<1><<<gg, 256, 0, stream>>>(accb, Wa, (float*)d_out, perm, off, N, bpt,
                                            denb, x, skip);
}

// Round 5
// 701.440 us; speedup vs baseline: 4.5510x; 1.7943x over previous
//
#include <hip/hip_runtime.h>
#include <math.h>

#define CDIM 256
#define HD 8
#define DD 32
#define NT 3
#define ET 5

typedef unsigned short u16;
typedef __attribute__((ext_vector_type(8))) short s16x8;
typedef __attribute__((ext_vector_type(4))) float f32x4;

__device__ __forceinline__ float b2f(u16 u) { return __uint_as_float(((unsigned)u) << 16); }
__device__ __forceinline__ u16 f2b(float x) {
    unsigned u = __float_as_uint(x);
    return (u16)((u + 0x7FFF + ((u >> 16) & 1)) >> 16);
}

// ================= node-type buckets (atomic-free, stable) =================
__global__ void bhist_k(const int* __restrict__ ntype, int N, int nblk, int* __restrict__ bcnt) {
    __shared__ int wc[4][NT];
    int b = blockIdx.x, tid = threadIdx.x, lane = tid & 63, w = tid >> 6;
    int i = b * 256 + tid;
    int t = (i < N) ? ntype[i] : -1;
#pragma unroll
    for (int r = 0; r < NT; ++r) {
        unsigned long long m = __ballot(t == r);
        if (lane == 0) wc[w][r] = __popcll(m);
    }
    __syncthreads();
    if (tid < NT) bcnt[tid * nblk + b] = wc[0][tid] + wc[1][tid] + wc[2][tid] + wc[3][tid];
}

__global__ void bscan_k(const int* __restrict__ bcnt, int* __restrict__ base,
                        int* __restrict__ off, int total, int nblk, int N) {
    __shared__ int s[1024];
    int t = threadIdx.x;
    int v = (t < total) ? bcnt[t] : 0;
    s[t] = v; __syncthreads();
    for (int o = 1; o < 1024; o <<= 1) {
        int u = (t >= o) ? s[t - o] : 0; __syncthreads();
        s[t] += u; __syncthreads();
    }
    if (t < total) base[t] = s[t] - v;
    if (t < NT) off[t] = s[t * nblk] - bcnt[t * nblk];
    if (t == NT) off[NT] = N;
}

__global__ void bscatter_k(const int* __restrict__ ntype, int N, int nblk,
                           const int* __restrict__ base, int* __restrict__ perm) {
    __shared__ int wc[4][NT];
    __shared__ int woff[4][NT];
    int b = blockIdx.x, tid = threadIdx.x, lane = tid & 63, w = tid >> 6;
    int i = b * 256 + tid;
    int t = (i < N) ? ntype[i] : -1;
    unsigned long long mlt = (1ULL << lane) - 1;
    int rank = 0;
#pragma unroll
    for (int r = 0; r < NT; ++r) {
        unsigned long long m = __ballot(t == r);
        if (lane == 0) wc[w][r] = __popcll(m);
        if (t == r) rank = __popcll(m & mlt);
    }
    __syncthreads();
    if (tid == 0) {
#pragma unroll
        for (int r = 0; r < NT; ++r) {
            int a = 0;
#pragma unroll
            for (int w0 = 0; w0 < 4; ++w0) { woff[w0][r] = a; a += wc[w0][r]; }
        }
    }
    __syncthreads();
    if (t >= 0) perm[base[t * nblk + b] + woff[w][t] + rank] = i;
}

// ================= edge counting sort by key = dst*ET + etype =================
__global__ void ehist_k(const int* __restrict__ dst, const int* __restrict__ etype, int E,
                        int* __restrict__ khist) {
    int i = blockIdx.x * 256 + threadIdx.x;
    if (i < E) atomicAdd(&khist[dst[i] * ET + etype[i]], 1);
}

__global__ void kscan1_k(const int* __restrict__ khist, int* __restrict__ kscan,
                         int* __restrict__ bsum, int KEYS) {
    __shared__ int s[256];
    int b = blockIdx.x, t = threadIdx.x, i = b * 256 + t;
    int v = (i < KEYS) ? khist[i] : 0;
    s[t] = v; __syncthreads();
    for (int o = 1; o < 256; o <<= 1) {
        int u = (t >= o) ? s[t - o] : 0; __syncthreads();
        s[t] += u; __syncthreads();
    }
    if (i < KEYS) kscan[i] = s[t] - v;
    if (t == 255) bsum[b] = s[t];
}

__global__ void kscan2_k(int* __restrict__ bsum, int NB) {
    __shared__ int s[1024];
    int t = threadIdx.x;
    int v = (t < NB) ? bsum[t] : 0;
    s[t] = v; __syncthreads();
    for (int o = 1; o < 1024; o <<= 1) {
        int u = (t >= o) ? s[t - o] : 0; __syncthreads();
        s[t] += u; __syncthreads();
    }
    if (t < NB) bsum[t] = s[t] - v;
}

__global__ void kscan3_k(int* __restrict__ kscan, const int* __restrict__ bsum, int KEYS) {
    int i = blockIdx.x * 256 + threadIdx.x;
    if (i < KEYS) kscan[i] += bsum[blockIdx.x];
}

__global__ void rowptr_k(const int* __restrict__ kscan, int* __restrict__ rowptr, int KEYS, int E) {
    int i = blockIdx.x * 256 + threadIdx.x;
    if (i < KEYS) rowptr[i] = kscan[i];
    if (i == KEYS) rowptr[KEYS] = E;
}

__global__ void escatter_k(const int* __restrict__ src, const int* __restrict__ dst,
                           const int* __restrict__ etype, int E,
                           int* __restrict__ kscan, int* __restrict__ epay) {
    int e = blockIdx.x * 256 + threadIdx.x;
    if (e < E) {
        int pos = atomicAdd(&kscan[dst[e] * ET + etype[e]], 1);
        epay[pos] = src[e];
    }
}

// ================= weight convert+transpose: W[t][k][c] f32 -> Wtb[t][c][k] bf16 ========
__global__ __launch_bounds__(256) void wconv_k(const float* __restrict__ W, u16* __restrict__ Wtb) {
    __shared__ u16 s[64][72];
    int k0 = blockIdx.x * 64, c0 = blockIdx.y * 64, t = blockIdx.z;
    const float* Wp = W + (size_t)t * CDIM * CDIM;
    int r = threadIdx.x >> 2, q = (threadIdx.x & 3) * 16;
#pragma unroll
    for (int m = 0; m < 16; m += 4) {
        float4 v = *(const float4*)(Wp + (size_t)(k0 + r) * CDIM + c0 + q + m);
        s[r][q + m + 0] = f2b(v.x); s[r][q + m + 1] = f2b(v.y);
        s[r][q + m + 2] = f2b(v.z); s[r][q + m + 3] = f2b(v.w);
    }
    __syncthreads();
    int c = threadIdx.x >> 2, kq = (threadIdx.x & 3) * 16;
    u16* op = Wtb + ((size_t)t * CDIM + c0 + c) * CDIM + k0 + kq;
#pragma unroll
    for (int m = 0; m < 16; m += 4) {
        ushort4 o;
        o.x = s[kq + m + 0][c]; o.y = s[kq + m + 1][c];
        o.z = s[kq + m + 2][c]; o.w = s[kq + m + 3][c];
        *(ushort4*)(op + m) = o;
    }
}

// ================= fp32 -> bf16 copy =================
__global__ void f2b_k(const float* __restrict__ in, u16* __restrict__ out, size_t n4) {
    size_t i = (size_t)blockIdx.x * 256 + threadIdx.x;
    if (i >= n4) return;
    float4 v = ((const float4*)in)[i];
    ushort4 o; o.x = f2b(v.x); o.y = f2b(v.y); o.z = f2b(v.z); o.w = f2b(v.w);
    ((ushort4*)out)[i] = o;
}

// ================= acc/denom -> bf16 (softmax denominator applied) =================
__global__ void hscale_k(const float* __restrict__ accb, const float* __restrict__ denb,
                         u16* __restrict__ hb, size_t n4) {
    size_t i = (size_t)blockIdx.x * 256 + threadIdx.x;
    if (i >= n4) return;
    size_t el = i * 4;
    int n = (int)(el >> 8), c = (int)(el & 255);
    float den = denb[n * HD + (c >> 5)];
    float sc = den > 0.f ? 1.f / den : 0.f;
    float4 v = ((const float4*)accb)[i];
    ushort4 o;
    o.x = f2b(v.x * sc); o.y = f2b(v.y * sc); o.z = f2b(v.z * sc); o.w = f2b(v.w * sc);
    ((ushort4*)hb)[i] = o;
}

// ================= MFMA typed GEMM: out[perm[r]] = A[perm[r]] @ W[t] =================
// A bf16 [N][256]; Wtb bf16 [NT][col][k]. MODE 0: bf16 out. MODE 1: f32 out, alpha-blend with x.
template<int MODE>
__global__ __launch_bounds__(256) void gemm_mfma_k(
    const u16* __restrict__ A, const u16* __restrict__ Wtb, void* __restrict__ outv,
    const int* __restrict__ perm, const int* __restrict__ off, int N, int bpt,
    const float* __restrict__ x, const float* __restrict__ skip)
{
    __shared__ u16 As[64][40];
    __shared__ u16 Bs[64][40];
    __shared__ int ridx[64];

    int t = blockIdx.x / bpt, bi = blockIdx.x % bpt;
    int i0 = off[t] + bi * 64, iend = off[t + 1];
    if (i0 >= iend) return;
    int tid = threadIdx.x;
    int col0 = blockIdx.y * 64;

    if (tid < 64) ridx[tid] = (i0 + tid < iend) ? perm[i0 + tid] : -1;
    __syncthreads();

    int sr = tid >> 2, sq = (tid & 3) * 8;     // staging: row-of-64, k-offset (8 bf16 = 16B)
    int ar = ridx[sr];
    const u16* asrc = A + (size_t)(ar >= 0 ? ar : 0) * CDIM + sq;
    const u16* bsrc = Wtb + ((size_t)t * CDIM + col0 + sr) * CDIM + sq;

    int lane = tid & 63, wid = tid >> 6;
    int wr = wid >> 1, wc = wid & 1;
    int l15 = lane & 15, lk = (lane >> 4) * 8;

    f32x4 acc00 = {0.f, 0.f, 0.f, 0.f}, acc01 = {0.f, 0.f, 0.f, 0.f};
    f32x4 acc10 = {0.f, 0.f, 0.f, 0.f}, acc11 = {0.f, 0.f, 0.f, 0.f};

    uint4 apre = make_uint4(0, 0, 0, 0), bpre;
    if (ar >= 0) apre = *(const uint4*)(asrc);
    bpre = *(const uint4*)(bsrc);

    for (int k0 = 0; k0 < CDIM; k0 += 32) {
        __syncthreads();
        *(uint4*)&As[sr][sq] = apre;
        *(uint4*)&Bs[sr][sq] = bpre;
        __syncthreads();

        if (k0 + 32 < CDIM) {
            if (ar >= 0) apre = *(const uint4*)(asrc + k0 + 32);
            bpre = *(const uint4*)(bsrc + k0 + 32);
        }

        s16x8 af0 = *(const s16x8*)&As[wr * 32 + l15][lk];
        s16x8 af1 = *(const s16x8*)&As[wr * 32 + 16 + l15][lk];
        s16x8 bf0 = *(const s16x8*)&Bs[wc * 32 + l15][lk];
        s16x8 bf1 = *(const s16x8*)&Bs[wc * 32 + 16 + l15][lk];

        acc00 = __builtin_amdgcn_mfma_f32_16x16x32_bf16(af0, bf0, acc00, 0, 0, 0);
        acc01 = __builtin_amdgcn_mfma_f32_16x16x32_bf16(af0, bf1, acc01, 0, 0, 0);
        acc10 = __builtin_amdgcn_mfma_f32_16x16x32_bf16(af1, bf0, acc10, 0, 0, 0);
        acc11 = __builtin_amdgcn_mfma_f32_16x16x32_bf16(af1, bf1, acc11, 0, 0, 0);
    }

    float alpha = 0.f, beta = 0.f;
    if (MODE == 1) {
        alpha = 1.f / (1.f + __expf(-skip[t]));
        beta = 1.f - alpha;
    }

    int rbase = wr * 32 + (lane >> 4) * 4;
#pragma unroll
    for (int mi = 0; mi < 2; ++mi) {
#pragma unroll
        for (int r = 0; r < 4; ++r) {
            int lrow = rbase + mi * 16 + r;
            int node = ridx[lrow];
            if (node < 0) continue;
            float v0 = (mi == 0) ? acc00[r] : acc10[r];
            float v1 = (mi == 0) ? acc01[r] : acc11[r];
            int c0i = col0 + wc * 32 + l15;
            if (MODE == 1) {
                float* out = (float*)outv;
                size_t b0 = (size_t)node * CDIM + c0i;
                out[b0]      = v0 * alpha + x[b0] * beta;
                out[b0 + 16] = v1 * alpha + x[b0 + 16] * beta;
            } else {
                u16* out = (u16*)outv;
                size_t b0 = (size_t)node * CDIM + c0i;
                out[b0]      = f2b(v0);
                out[b0 + 16] = f2b(v1);
            }
        }
    }
}

// ================= per-et dense q transform =================
__global__ __launch_bounds__(256) void relq_k(
    const u16* __restrict__ qb, const float* __restrict__ Ratt,
    u16* __restrict__ qw, int N, int et)
{
    __shared__ float Rs[DD][DD];
    __shared__ float ts[64][DD + 1];

    int h = blockIdx.y;
    int n0 = blockIdx.x * 64;
    int tid = threadIdx.x;

    {
        const float* Rp = Ratt + ((size_t)(et * HD + h)) * (DD * DD);
        float4 rv = ((const float4*)Rp)[tid];
        int r = tid >> 3, c4 = (tid & 7) * 4;
        Rs[c4 + 0][r] = rv.x; Rs[c4 + 1][r] = rv.y;
        Rs[c4 + 2][r] = rv.z; Rs[c4 + 3][r] = rv.w;
    }
    {
        int r = tid >> 2, c8 = (tid & 3) * 8;
        int n = n0 + r;
        if (n < N) {
            const u16* ip = qb + (size_t)n * CDIM + h * DD + c8;
            ushort4 a = *(const ushort4*)ip;
            ushort4 b = *(const ushort4*)(ip + 4);
            ts[r][c8 + 0] = b2f(a.x); ts[r][c8 + 1] = b2f(a.y);
            ts[r][c8 + 2] = b2f(a.z); ts[r][c8 + 3] = b2f(a.w);
            ts[r][c8 + 4] = b2f(b.x); ts[r][c8 + 5] = b2f(b.y);
            ts[r][c8 + 6] = b2f(b.z); ts[r][c8 + 7] = b2f(b.w);
        } else {
#pragma unroll
            for (int m = 0; m < 8; ++m) ts[r][c8 + m] = 0.f;
        }
    }
    __syncthreads();

    int nl = tid >> 2, fq = tid & 3;
    int n = n0 + nl;
    float acc[8] = {};
#pragma unroll
    for (int c = 0; c < DD; ++c) {
        float xv = ts[nl][c];
#pragma unroll
        for (int jj = 0; jj < 8; ++jj)
            acc[jj] += xv * Rs[c][fq * 8 + jj];
    }
    if (n < N) {
        u16* op = qw + (size_t)n * CDIM + h * DD + fq * 8;
        ushort4 o0, o1;
        o0.x = f2b(acc[0]); o0.y = f2b(acc[1]); o0.z = f2b(acc[2]); o0.w = f2b(acc[3]);
        o1.x = f2b(acc[4]); o1.y = f2b(acc[5]); o1.z = f2b(acc[6]); o1.w = f2b(acc[7]);
        *(ushort4*)op = o0;
        *(ushort4*)(op + 4) = o1;
    }
}

// ================= per-et gather =================
__global__ __launch_bounds__(256) void gather_et_k(
    const u16* __restrict__ kb, const u16* __restrict__ vb, const u16* __restrict__ qw,
    const float* __restrict__ Rmsg, const float* __restrict__ pri,
    const int* __restrict__ rowptr, const int* __restrict__ epay,
    float* __restrict__ acc, float* __restrict__ den, int N, int et)
{
    __shared__ float Rm_s[HD * 1057];

    int tid = threadIdx.x;
    {
        const float* Rp = Rmsg + (size_t)et * HD * DD * DD;
        for (int i = tid; i < HD * DD * DD; i += 256) {
            int h = i >> 10, f = (i >> 5) & 31, d = i & 31;
            Rm_s[h * 1057 + f * 33 + d] = Rp[i];
        }
    }
    __syncthreads();

    int lane = tid & 63;
    int wv = tid >> 6;
    int h = lane >> 3, j = lane & 7;
    float prif = pri[et * HD + h] * 0.17677669529663687f;
    int dbase = blockIdx.x * 64 + wv * 16;

    for (int slot = 0; slot < 16; ++slot) {
        int d = dbase + slot;
        if (d >= N) break;
        int key = d * ET + et;
        int p0 = rowptr[key], p1 = rowptr[key + 1];
        if (p0 == p1) continue;

        ushort4 qwu = *(const ushort4*)(qw + (size_t)d * CDIM + lane * 4);
        float qf0 = b2f(qwu.x), qf1 = b2f(qwu.y), qf2 = b2f(qwu.z), qf3 = b2f(qwu.w);

        float Sv0 = 0.f, Sv1 = 0.f, Sv2 = 0.f, Sv3 = 0.f, dsum = 0.f;
        for (int p = p0; p < p1; ++p) {
            int s = epay[p];
            ushort4 ku = *(const ushort4*)(kb + (size_t)s * CDIM + lane * 4);
            float t = b2f(ku.x) * qf0 + b2f(ku.y) * qf1 + b2f(ku.z) * qf2 + b2f(ku.w) * qf3;
            t += __shfl_xor(t, 1, 8);
            t += __shfl_xor(t, 2, 8);
            t += __shfl_xor(t, 4, 8);
            float ex = __expf(t * prif);
            ushort4 vu = *(const ushort4*)(vb + (size_t)s * CDIM + lane * 4);
            Sv0 += ex * b2f(vu.x); Sv1 += ex * b2f(vu.y);
            Sv2 += ex * b2f(vu.z); Sv3 += ex * b2f(vu.w);
            dsum += ex;
        }

        float o0 = 0.f, o1 = 0.f, o2 = 0.f, o3 = 0.f;
        const float* rb = &Rm_s[h * 1057 + j * 4];
#pragma unroll
        for (int f = 0; f < DD; ++f) {
            int srcl = h * 8 + (f >> 2);
            float sf;
            switch (f & 3) {
                case 0:  sf = __shfl(Sv0, srcl, 64); break;
                case 1:  sf = __shfl(Sv1, srcl, 64); break;
                case 2:  sf = __shfl(Sv2, srcl, 64); break;
                default: sf = __shfl(Sv3, srcl, 64); break;
            }
            o0 += sf * rb[f * 33 + 0];
            o1 += sf * rb[f * 33 + 1];
            o2 += sf * rb[f * 33 + 2];
            o3 += sf * rb[f * 33 + 3];
        }

        float* ap = acc + (size_t)d * CDIM + lane * 4;
        float4 av = *(float4*)ap;
        av.x += o0; av.y += o1; av.z += o2; av.w += o3;
        *(float4*)ap = av;
        if (j == 0) den[d * HD + h] += dsum;
    }
}

// ================= launch =================
extern "C" void kernel_launch(void* const* d_in, const int* in_sizes, int n_in,
                              void* d_out, int out_size, void* d_ws, size_t ws_size,
                              hipStream_t stream) {
    const float* x    = (const float*)d_in[0];
    const float* Wk   = (const float*)d_in[1];
    const float* Wq   = (const float*)d_in[2];
    const float* Wv   = (const float*)d_in[3];
    const float* Ratt = (const float*)d_in[4];
    const float* Rmsg = (const float*)d_in[5];
    const float* pri  = (const float*)d_in[6];
    const float* Wa   = (const float*)d_in[7];
    const float* skip = (const float*)d_in[8];
    const int* src   = (const int*)d_in[9];
    const int* dst   = (const int*)d_in[10];
    const int* etype = (const int*)d_in[11];
    const int* ntype = (const int*)d_in[12];

    int N = in_sizes[12];
    int E = in_sizes[9];
    const size_t NC = (size_t)N * CDIM;
    const int KEYS = N * ET;
    const int NB = (KEYS + 255) / 256;
    const int nblk = (N + 255) / 256;
    const size_t WTE = (size_t)NT * CDIM * CDIM;   // u16 elems per weight tensor

    // ---- workspace (~187 MB) ----
    float* accb = (float*)d_ws;                  // NC f32
    float* denb = accb + NC;                     // N*HD f32
    u16* kb  = (u16*)(denb + (size_t)N * HD);    // NC bf16
    u16* qb  = kb + NC;
    u16* vb  = qb + NC;
    u16* qw  = vb + NC;                          // reused per et
    u16* xb  = qw + NC;                          // bf16(x); reused as hb later
    u16* wtb = xb + NC;                          // 4 * WTE bf16 (Wk,Wq,Wv,Wa)
    int* khist  = (int*)(wtb + 4 * WTE);         // KEYS (zeroed)
    int* kscan  = khist + KEYS;                  // KEYS
    int* bsum   = kscan + KEYS;                  // 1024
    int* rowptr = bsum + 1024;                   // KEYS+1
    int* perm   = rowptr + KEYS + 1;             // N
    int* epay   = perm + N;                      // E
    int* bcnt   = epay + E;                      // NT*nblk
    int* base   = bcnt + NT * nblk;              // NT*nblk
    int* off    = base + NT * nblk;              // 4
    u16* hb = xb;

    hipMemsetAsync(accb, 0, (NC + (size_t)N * HD) * sizeof(float), stream);
    hipMemsetAsync(khist, 0, (size_t)KEYS * sizeof(int), stream);

    // node buckets (atomic-free, stable)
    bhist_k<<<nblk, 256, 0, stream>>>(ntype, N, nblk, bcnt);
    bscan_k<<<1, 1024, 0, stream>>>(bcnt, base, off, NT * nblk, nblk, N);
    bscatter_k<<<nblk, 256, 0, stream>>>(ntype, N, nblk, base, perm);

    // edge counting sort by (dst, etype) -> CSR
    ehist_k<<<(E + 255) / 256, 256, 0, stream>>>(dst, etype, E, khist);
    kscan1_k<<<NB, 256, 0, stream>>>(khist, kscan, bsum, KEYS);
    kscan2_k<<<1, 1024, 0, stream>>>(bsum, NB);
    kscan3_k<<<NB, 256, 0, stream>>>(kscan, bsum, KEYS);
    rowptr_k<<<(KEYS + 256) / 256, 256, 0, stream>>>(kscan, rowptr, KEYS, E);
    escatter_k<<<(E + 255) / 256, 256, 0, stream>>>(src, dst, etype, E, kscan, epay);

    // weights -> bf16 transposed [t][c][k]
    dim3 wg(4, 4, NT);
    wconv_k<<<wg, 256, 0, stream>>>(Wk, wtb + 0 * WTE);
    wconv_k<<<wg, 256, 0, stream>>>(Wq, wtb + 1 * WTE);
    wconv_k<<<wg, 256, 0, stream>>>(Wv, wtb + 2 * WTE);
    wconv_k<<<wg, 256, 0, stream>>>(Wa, wtb + 3 * WTE);

    // x -> bf16
    size_t n4 = NC / 4;
    f2b_k<<<(int)((n4 + 255) / 256), 256, 0, stream>>>(x, xb, n4);

    // k/q/v projections (MFMA)
    int bpt = (N + 63) / 64;
    dim3 gg(NT * bpt, CDIM / 64);
    gemm_mfma_k<0><<<gg, 256, 0, stream>>>(xb, wtb + 0 * WTE, kb, perm, off, N, bpt, nullptr, nullptr);
    gemm_mfma_k<0><<<gg, 256, 0, stream>>>(xb, wtb + 1 * WTE, qb, perm, off, N, bpt, nullptr, nullptr);
    gemm_mfma_k<0><<<gg, 256, 0, stream>>>(xb, wtb + 2 * WTE, vb, perm, off, N, bpt, nullptr, nullptr);

    // per-etype: dense q transform + gather (stream-serialized -> no races)
    int gblocks = (N + 63) / 64;
    for (int et = 0; et < ET; ++et) {
        dim3 rg(gblocks, HD);
        relq_k<<<rg, 256, 0, stream>>>(qb, Ratt, qw, N, et);
        gather_et_k<<<gblocks, 256, 0, stream>>>(kb, vb, qw, Rmsg, pri, rowptr, epay,
                                                 accb, denb, N, et);
    }

    // h = acc/denom -> bf16 (reuses xb)
    hscale_k<<<(int)((n4 + 255) / 256), 256, 0, stream>>>(accb, denb, hb, n4);

    // output projection + gated skip (MFMA)
    gemm_mfma_k<1><<<gg, 256, 0, stream>>>(hb, wtb + 3 * WTE, (float*)d_out, perm, off, N, bpt,
                                           x, skip);
}

// Round 6
// 476.899 us; speedup vs baseline: 6.6937x; 1.4708x over previous
//
#include <hip/hip_runtime.h>
#include <math.h>

#define CDIM 256
#define HD 8
#define DD 32
#define NT 3
#define ET 5

typedef unsigned short u16;
typedef __attribute__((ext_vector_type(8))) short s16x8;
typedef __attribute__((ext_vector_type(4))) float f32x4;

__device__ __forceinline__ float b2f(u16 u) { return __uint_as_float(((unsigned)u) << 16); }
__device__ __forceinline__ u16 f2b(float x) {
    unsigned u = __float_as_uint(x);
    return (u16)((u + 0x7FFF + ((u >> 16) & 1)) >> 16);
}

// ================= node-type buckets (atomic-free, stable) =================
__global__ void bhist_k(const int* __restrict__ ntype, int N, int nblk, int* __restrict__ bcnt) {
    __shared__ int wc[4][NT];
    int b = blockIdx.x, tid = threadIdx.x, lane = tid & 63, w = tid >> 6;
    int i = b * 256 + tid;
    int t = (i < N) ? ntype[i] : -1;
#pragma unroll
    for (int r = 0; r < NT; ++r) {
        unsigned long long m = __ballot(t == r);
        if (lane == 0) wc[w][r] = __popcll(m);
    }
    __syncthreads();
    if (tid < NT) bcnt[tid * nblk + b] = wc[0][tid] + wc[1][tid] + wc[2][tid] + wc[3][tid];
}

__global__ void bscan_k(const int* __restrict__ bcnt, int* __restrict__ base,
                        int* __restrict__ off, int total, int nblk, int N) {
    __shared__ int s[1024];
    int t = threadIdx.x;
    int v = (t < total) ? bcnt[t] : 0;
    s[t] = v; __syncthreads();
    for (int o = 1; o < 1024; o <<= 1) {
        int u = (t >= o) ? s[t - o] : 0; __syncthreads();
        s[t] += u; __syncthreads();
    }
    if (t < total) base[t] = s[t] - v;
    if (t < NT) off[t] = s[t * nblk] - bcnt[t * nblk];
    if (t == NT) off[NT] = N;
}

__global__ void bscatter_k(const int* __restrict__ ntype, int N, int nblk,
                           const int* __restrict__ base, int* __restrict__ perm) {
    __shared__ int wc[4][NT];
    __shared__ int woff[4][NT];
    int b = blockIdx.x, tid = threadIdx.x, lane = tid & 63, w = tid >> 6;
    int i = b * 256 + tid;
    int t = (i < N) ? ntype[i] : -1;
    unsigned long long mlt = (1ULL << lane) - 1;
    int rank = 0;
#pragma unroll
    for (int r = 0; r < NT; ++r) {
        unsigned long long m = __ballot(t == r);
        if (lane == 0) wc[w][r] = __popcll(m);
        if (t == r) rank = __popcll(m & mlt);
    }
    __syncthreads();
    if (tid == 0) {
#pragma unroll
        for (int r = 0; r < NT; ++r) {
            int a = 0;
#pragma unroll
            for (int w0 = 0; w0 < 4; ++w0) { woff[w0][r] = a; a += wc[w0][r]; }
        }
    }
    __syncthreads();
    if (t >= 0) perm[base[t * nblk + b] + woff[w][t] + rank] = i;
}

// ================= edge counting sort by key = dst*ET + etype =================
__global__ void ehist_k(const int* __restrict__ dst, const int* __restrict__ etype, int E,
                        int* __restrict__ khist) {
    int i = blockIdx.x * 256 + threadIdx.x;
    if (i < E) atomicAdd(&khist[dst[i] * ET + etype[i]], 1);
}

__global__ void kscan1_k(const int* __restrict__ khist, int* __restrict__ kscan,
                         int* __restrict__ bsum, int KEYS) {
    __shared__ int s[256];
    int b = blockIdx.x, t = threadIdx.x, i = b * 256 + t;
    int v = (i < KEYS) ? khist[i] : 0;
    s[t] = v; __syncthreads();
    for (int o = 1; o < 256; o <<= 1) {
        int u = (t >= o) ? s[t - o] : 0; __syncthreads();
        s[t] += u; __syncthreads();
    }
    if (i < KEYS) kscan[i] = s[t] - v;
    if (t == 255) bsum[b] = s[t];
}

__global__ void kscan2_k(int* __restrict__ bsum, int NB) {
    __shared__ int s[1024];
    int t = threadIdx.x;
    int v = (t < NB) ? bsum[t] : 0;
    s[t] = v; __syncthreads();
    for (int o = 1; o < 1024; o <<= 1) {
        int u = (t >= o) ? s[t - o] : 0; __syncthreads();
        s[t] += u; __syncthreads();
    }
    if (t < NB) bsum[t] = s[t] - v;
}

__global__ void kscan3_k(int* __restrict__ kscan, const int* __restrict__ bsum, int KEYS) {
    int i = blockIdx.x * 256 + threadIdx.x;
    if (i < KEYS) kscan[i] += bsum[blockIdx.x];
}

__global__ void rowptr_k(const int* __restrict__ kscan, int* __restrict__ rowptr, int KEYS, int E) {
    int i = blockIdx.x * 256 + threadIdx.x;
    if (i < KEYS) rowptr[i] = kscan[i];
    if (i == KEYS) rowptr[KEYS] = E;
}

__global__ void escatter_k(const int* __restrict__ src, const int* __restrict__ dst,
                           const int* __restrict__ etype, int E,
                           int* __restrict__ kscan, int* __restrict__ epay) {
    int e = blockIdx.x * 256 + threadIdx.x;
    if (e < E) {
        int pos = atomicAdd(&kscan[dst[e] * ET + etype[e]], 1);
        epay[pos] = src[e];
    }
}

// ================= weight convert+transpose: W[t][k][c] f32 -> Wtb[t][c][k] bf16 ========
__global__ __launch_bounds__(256) void wconv_k(const float* __restrict__ W, u16* __restrict__ Wtb) {
    __shared__ u16 s[64][72];
    int k0 = blockIdx.x * 64, c0 = blockIdx.y * 64, t = blockIdx.z;
    const float* Wp = W + (size_t)t * CDIM * CDIM;
    int r = threadIdx.x >> 2, q = (threadIdx.x & 3) * 16;
#pragma unroll
    for (int m = 0; m < 16; m += 4) {
        float4 v = *(const float4*)(Wp + (size_t)(k0 + r) * CDIM + c0 + q + m);
        s[r][q + m + 0] = f2b(v.x); s[r][q + m + 1] = f2b(v.y);
        s[r][q + m + 2] = f2b(v.z); s[r][q + m + 3] = f2b(v.w);
    }
    __syncthreads();
    int c = threadIdx.x >> 2, kq = (threadIdx.x & 3) * 16;
    u16* op = Wtb + ((size_t)t * CDIM + c0 + c) * CDIM + k0 + kq;
#pragma unroll
    for (int m = 0; m < 16; m += 4) {
        ushort4 o;
        o.x = s[kq + m + 0][c]; o.y = s[kq + m + 1][c];
        o.z = s[kq + m + 2][c]; o.w = s[kq + m + 3][c];
        *(ushort4*)(op + m) = o;
    }
}

// ================= fp32 -> bf16 copy =================
__global__ void f2b_k(const float* __restrict__ in, u16* __restrict__ out, size_t n4) {
    size_t i = (size_t)blockIdx.x * 256 + threadIdx.x;
    if (i >= n4) return;
    float4 v = ((const float4*)in)[i];
    ushort4 o; o.x = f2b(v.x); o.y = f2b(v.y); o.z = f2b(v.z); o.w = f2b(v.w);
    ((ushort4*)out)[i] = o;
}

// ================= R transforms -> bf16, f-major [et][f][h*32+m] =================
// ra_t[et][f][h][m] = Ratt[et][h][m][f]   (so qw matvec reads contiguous in (h,m))
// rm_t[et][f][h][m] = Rmsg[et][h][f][m]
__global__ void rt_k(const float* __restrict__ Ratt, const float* __restrict__ Rmsg,
                     u16* __restrict__ ra_t, u16* __restrict__ rm_t) {
    int o = blockIdx.x * 256 + threadIdx.x;
    if (o >= ET * DD * HD * DD) return;
    int m = o & 31, h2 = (o >> 5) & 7, f = (o >> 8) & 31, et = o >> 13;
    ra_t[o] = f2b(Ratt[(((et * 8 + h2) * 32 + m) * 32) + f]);
    rm_t[o] = f2b(Rmsg[(((et * 8 + h2) * 32 + f) * 32) + m]);
}

// ================= MFMA typed GEMM: out[perm[r]] = A[perm[r]] @ W[t] =================
template<int MODE>
__global__ __launch_bounds__(256) void gemm_mfma_k(
    const u16* __restrict__ A, const u16* __restrict__ Wtb, void* __restrict__ outv,
    const int* __restrict__ perm, const int* __restrict__ off, int N, int bpt,
    const float* __restrict__ x, const float* __restrict__ skip)
{
    __shared__ u16 As[64][40];
    __shared__ u16 Bs[64][40];
    __shared__ int ridx[64];

    int t = blockIdx.x / bpt, bi = blockIdx.x % bpt;
    int i0 = off[t] + bi * 64, iend = off[t + 1];
    if (i0 >= iend) return;
    int tid = threadIdx.x;
    int col0 = blockIdx.y * 64;

    if (tid < 64) ridx[tid] = (i0 + tid < iend) ? perm[i0 + tid] : -1;
    __syncthreads();

    int sr = tid >> 2, sq = (tid & 3) * 8;
    int ar = ridx[sr];
    const u16* asrc = A + (size_t)(ar >= 0 ? ar : 0) * CDIM + sq;
    const u16* bsrc = Wtb + ((size_t)t * CDIM + col0 + sr) * CDIM + sq;

    int lane = tid & 63, wid = tid >> 6;
    int wr = wid >> 1, wc = wid & 1;
    int l15 = lane & 15, lk = (lane >> 4) * 8;

    f32x4 acc00 = {0.f, 0.f, 0.f, 0.f}, acc01 = {0.f, 0.f, 0.f, 0.f};
    f32x4 acc10 = {0.f, 0.f, 0.f, 0.f}, acc11 = {0.f, 0.f, 0.f, 0.f};

    uint4 apre = make_uint4(0, 0, 0, 0), bpre;
    if (ar >= 0) apre = *(const uint4*)(asrc);
    bpre = *(const uint4*)(bsrc);

    for (int k0 = 0; k0 < CDIM; k0 += 32) {
        __syncthreads();
        *(uint4*)&As[sr][sq] = apre;
        *(uint4*)&Bs[sr][sq] = bpre;
        __syncthreads();

        if (k0 + 32 < CDIM) {
            if (ar >= 0) apre = *(const uint4*)(asrc + k0 + 32);
            bpre = *(const uint4*)(bsrc + k0 + 32);
        }

        s16x8 af0 = *(const s16x8*)&As[wr * 32 + l15][lk];
        s16x8 af1 = *(const s16x8*)&As[wr * 32 + 16 + l15][lk];
        s16x8 bf0 = *(const s16x8*)&Bs[wc * 32 + l15][lk];
        s16x8 bf1 = *(const s16x8*)&Bs[wc * 32 + 16 + l15][lk];

        acc00 = __builtin_amdgcn_mfma_f32_16x16x32_bf16(af0, bf0, acc00, 0, 0, 0);
        acc01 = __builtin_amdgcn_mfma_f32_16x16x32_bf16(af0, bf1, acc01, 0, 0, 0);
        acc10 = __builtin_amdgcn_mfma_f32_16x16x32_bf16(af1, bf0, acc10, 0, 0, 0);
        acc11 = __builtin_amdgcn_mfma_f32_16x16x32_bf16(af1, bf1, acc11, 0, 0, 0);
    }

    float alpha = 0.f, beta = 0.f;
    if (MODE == 1) {
        alpha = 1.f / (1.f + __expf(-skip[t]));
        beta = 1.f - alpha;
    }

    int rbase = wr * 32 + (lane >> 4) * 4;
#pragma unroll
    for (int mi = 0; mi < 2; ++mi) {
#pragma unroll
        for (int r = 0; r < 4; ++r) {
            int lrow = rbase + mi * 16 + r;
            int node = ridx[lrow];
            if (node < 0) continue;
            float v0 = (mi == 0) ? acc00[r] : acc10[r];
            float v1 = (mi == 0) ? acc01[r] : acc11[r];
            int c0i = col0 + wc * 32 + l15;
            if (MODE == 1) {
                float* out = (float*)outv;
                size_t b0 = (size_t)node * CDIM + c0i;
                out[b0]      = v0 * alpha + x[b0] * beta;
                out[b0 + 16] = v1 * alpha + x[b0 + 16] * beta;
            } else {
                u16* out = (u16*)outv;
                size_t b0 = (size_t)node * CDIM + c0i;
                out[b0]      = f2b(v0);
                out[b0 + 16] = f2b(v1);
            }
        }
    }
}

// ================= fused gather: one wave per 4 dst, all 5 etypes, reg accumulation ====
// per (d,et) non-empty: qw = Ratt[et] @ q[d]; loop edges {logit, exp, Sv += ex*v[src]};
// o += Sv @ Rmsg[et]; den += sum ex.  Final: hb[d] = bf16(o / den).
__global__ __launch_bounds__(256) void gather_all_k(
    const u16* __restrict__ kb, const u16* __restrict__ qb, const u16* __restrict__ vb,
    const u16* __restrict__ ra_t, const u16* __restrict__ rm_t, const float* __restrict__ pri,
    const int* __restrict__ rowptr, const int* __restrict__ epay,
    u16* __restrict__ hb, int N)
{
    __shared__ u16 Ra_s[DD * CDIM];   // [f][h*32+m] bf16, 16 KB
    __shared__ u16 Rm_s[DD * CDIM];   // 16 KB

    int tid = threadIdx.x, lane = tid & 63, wv = tid >> 6;
    int h = lane >> 3;
    int dbase = blockIdx.x * 16 + wv * 4;

    float o[4][4] = {};
    float den[4] = {};
    const float rsD = 0.17677669529663687f;

    for (int et = 0; et < ET; ++et) {
        __syncthreads();
        {
            const uint4* rs = (const uint4*)(ra_t + (size_t)et * (DD * CDIM));
            const uint4* ms = (const uint4*)(rm_t + (size_t)et * (DD * CDIM));
            uint4* rl = (uint4*)Ra_s;
            uint4* ml = (uint4*)Rm_s;
#pragma unroll
            for (int i = 0; i < 4; ++i) {
                rl[i * 256 + tid] = rs[i * 256 + tid];
                ml[i * 256 + tid] = ms[i * 256 + tid];
            }
        }
        __syncthreads();
        float prif = pri[et * HD + h] * rsD;

#pragma unroll
        for (int s = 0; s < 4; ++s) {
            int d = dbase + s;
            if (d >= N) continue;
            int key = d * ET + et;
            int p0 = rowptr[key], p1 = rowptr[key + 1];
            if (p0 >= p1) continue;

            // load q[d] (this wave's 4-dim slice per lane)
            ushort4 qu = *(const ushort4*)(qb + (size_t)d * CDIM + lane * 4);
            float q0 = b2f(qu.x), q1 = b2f(qu.y), q2 = b2f(qu.z), q3 = b2f(qu.w);

            // qw[m] = sum_f Ratt[h][m][f] * q[h][f]   (Ra_s[f][h*32+m])
            float qw0 = 0.f, qw1 = 0.f, qw2 = 0.f, qw3 = 0.f;
#pragma unroll 4
            for (int f = 0; f < DD; ++f) {
                float qs;
                switch (f & 3) {
                    case 0:  qs = q0; break;
                    case 1:  qs = q1; break;
                    case 2:  qs = q2; break;
                    default: qs = q3; break;
                }
                float qf = __shfl(qs, h * 8 + (f >> 2), 64);
                ushort4 rv = *(const ushort4*)&Ra_s[f * CDIM + lane * 4];
                qw0 += qf * b2f(rv.x); qw1 += qf * b2f(rv.y);
                qw2 += qf * b2f(rv.z); qw3 += qf * b2f(rv.w);
            }

            float Sv0 = 0.f, Sv1 = 0.f, Sv2 = 0.f, Sv3 = 0.f, ds = 0.f;
            for (int p = p0; p < p1; ++p) {
                int srcn = epay[p];
                ushort4 ku = *(const ushort4*)(kb + (size_t)srcn * CDIM + lane * 4);
                float t = b2f(ku.x) * qw0 + b2f(ku.y) * qw1 + b2f(ku.z) * qw2 + b2f(ku.w) * qw3;
                t += __shfl_xor(t, 1, 8);
                t += __shfl_xor(t, 2, 8);
                t += __shfl_xor(t, 4, 8);
                float ex = __expf(t * prif);
                ushort4 vu = *(const ushort4*)(vb + (size_t)srcn * CDIM + lane * 4);
                Sv0 += ex * b2f(vu.x); Sv1 += ex * b2f(vu.y);
                Sv2 += ex * b2f(vu.z); Sv3 += ex * b2f(vu.w);
                ds += ex;
            }
            den[s] += ds;

            // o[m] += sum_f Sv[h][f] * Rmsg[h][f][m]   (Rm_s[f][h*32+m])
#pragma unroll 4
            for (int f = 0; f < DD; ++f) {
                int srcl = h * 8 + (f >> 2);
                float sf;
                switch (f & 3) {
                    case 0:  sf = __shfl(Sv0, srcl, 64); break;
                    case 1:  sf = __shfl(Sv1, srcl, 64); break;
                    case 2:  sf = __shfl(Sv2, srcl, 64); break;
                    default: sf = __shfl(Sv3, srcl, 64); break;
                }
                ushort4 rv = *(const ushort4*)&Rm_s[f * CDIM + lane * 4];
                o[s][0] += sf * b2f(rv.x); o[s][1] += sf * b2f(rv.y);
                o[s][2] += sf * b2f(rv.z); o[s][3] += sf * b2f(rv.w);
            }
        }
    }

#pragma unroll
    for (int s = 0; s < 4; ++s) {
        int d = dbase + s;
        if (d >= N) continue;
        float sc = den[s] > 0.f ? 1.f / den[s] : 0.f;
        ushort4 ov;
        ov.x = f2b(o[s][0] * sc); ov.y = f2b(o[s][1] * sc);
        ov.z = f2b(o[s][2] * sc); ov.w = f2b(o[s][3] * sc);
        *(ushort4*)(hb + (size_t)d * CDIM + lane * 4) = ov;
    }
}

// ================= launch =================
extern "C" void kernel_launch(void* const* d_in, const int* in_sizes, int n_in,
                              void* d_out, int out_size, void* d_ws, size_t ws_size,
                              hipStream_t stream) {
    const float* x    = (const float*)d_in[0];
    const float* Wk   = (const float*)d_in[1];
    const float* Wq   = (const float*)d_in[2];
    const float* Wv   = (const float*)d_in[3];
    const float* Ratt = (const float*)d_in[4];
    const float* Rmsg = (const float*)d_in[5];
    const float* pri  = (const float*)d_in[6];
    const float* Wa   = (const float*)d_in[7];
    const float* skip = (const float*)d_in[8];
    const int* src   = (const int*)d_in[9];
    const int* dst   = (const int*)d_in[10];
    const int* etype = (const int*)d_in[11];
    const int* ntype = (const int*)d_in[12];

    int N = in_sizes[12];
    int E = in_sizes[9];
    const size_t NC = (size_t)N * CDIM;
    const int KEYS = N * ET;
    const int NB = (KEYS + 255) / 256;
    const int nblk = (N + 255) / 256;
    const size_t WTE = (size_t)NT * CDIM * CDIM;
    const size_t RTE = (size_t)ET * DD * HD * DD;   // 40960

    // ---- workspace (~112 MB) ----
    u16* kb   = (u16*)d_ws;                      // NC
    u16* qb   = kb + NC;                         // NC
    u16* vb   = qb + NC;                         // NC
    u16* xb   = vb + NC;                         // NC (reused as hb)
    u16* wtb  = xb + NC;                         // 4*WTE
    u16* ra_t = wtb + 4 * WTE;                   // RTE
    u16* rm_t = ra_t + RTE;                      // RTE
    int* khist  = (int*)(rm_t + RTE);            // KEYS (zeroed)
    int* kscan  = khist + KEYS;                  // KEYS
    int* bsum   = kscan + KEYS;                  // 1024
    int* rowptr = bsum + 1024;                   // KEYS+1
    int* perm   = rowptr + KEYS + 1;             // N
    int* epay   = perm + N;                      // E
    int* bcnt   = epay + E;                      // NT*nblk
    int* base   = bcnt + NT * nblk;              // NT*nblk
    int* off    = base + NT * nblk;              // NT+1
    u16* hb = xb;

    hipMemsetAsync(khist, 0, (size_t)KEYS * sizeof(int), stream);

    // node buckets (atomic-free, stable)
    bhist_k<<<nblk, 256, 0, stream>>>(ntype, N, nblk, bcnt);
    bscan_k<<<1, 1024, 0, stream>>>(bcnt, base, off, NT * nblk, nblk, N);
    bscatter_k<<<nblk, 256, 0, stream>>>(ntype, N, nblk, base, perm);

    // edge counting sort by (dst, etype) -> CSR
    ehist_k<<<(E + 255) / 256, 256, 0, stream>>>(dst, etype, E, khist);
    kscan1_k<<<NB, 256, 0, stream>>>(khist, kscan, bsum, KEYS);
    kscan2_k<<<1, 1024, 0, stream>>>(bsum, NB);
    kscan3_k<<<NB, 256, 0, stream>>>(kscan, bsum, KEYS);
    rowptr_k<<<(KEYS + 256) / 256, 256, 0, stream>>>(kscan, rowptr, KEYS, E);
    escatter_k<<<(E + 255) / 256, 256, 0, stream>>>(src, dst, etype, E, kscan, epay);

    // weights -> bf16 transposed [t][c][k]; R -> bf16 f-major; x -> bf16
    dim3 wg(4, 4, NT);
    wconv_k<<<wg, 256, 0, stream>>>(Wk, wtb + 0 * WTE);
    wconv_k<<<wg, 256, 0, stream>>>(Wq, wtb + 1 * WTE);
    wconv_k<<<wg, 256, 0, stream>>>(Wv, wtb + 2 * WTE);
    wconv_k<<<wg, 256, 0, stream>>>(Wa, wtb + 3 * WTE);
    rt_k<<<(int)((RTE + 255) / 256), 256, 0, stream>>>(Ratt, Rmsg, ra_t, rm_t);
    size_t n4 = NC / 4;
    f2b_k<<<(int)((n4 + 255) / 256), 256, 0, stream>>>(x, xb, n4);

    // k/q/v projections (MFMA)
    int bpt = (N + 63) / 64;
    dim3 gg(NT * bpt, CDIM / 64);
    gemm_mfma_k<0><<<gg, 256, 0, stream>>>(xb, wtb + 0 * WTE, kb, perm, off, N, bpt, nullptr, nullptr);
    gemm_mfma_k<0><<<gg, 256, 0, stream>>>(xb, wtb + 1 * WTE, qb, perm, off, N, bpt, nullptr, nullptr);
    gemm_mfma_k<0><<<gg, 256, 0, stream>>>(xb, wtb + 2 * WTE, vb, perm, off, N, bpt, nullptr, nullptr);

    // fused gather (single launch, all etypes, no atomics, writes hb with 1/den applied)
    gather_all_k<<<(N + 15) / 16, 256, 0, stream>>>(kb, qb, vb, ra_t, rm_t, pri,
                                                    rowptr, epay, hb, N);

    // output projection + gated skip (MFMA)
    gemm_mfma_k<1><<<gg, 256, 0, stream>>>(hb, wtb + 3 * WTE, (float*)d_out, perm, off, N, bpt,
                                           x, skip);
}

// Round 7
// 471.145 us; speedup vs baseline: 6.7755x; 1.0122x over previous
//
#include <hip/hip_runtime.h>
#include <math.h>

#define CDIM 256
#define HD 8
#define DD 32
#define NT 3
#define ET 5

typedef unsigned short u16;
typedef __attribute__((ext_vector_type(8))) short s16x8;
typedef __attribute__((ext_vector_type(4))) float f32x4;

__device__ __forceinline__ float b2f(u16 u) { return __uint_as_float(((unsigned)u) << 16); }
__device__ __forceinline__ u16 f2b(float x) {
    unsigned u = __float_as_uint(x);
    return (u16)((u + 0x7FFF + ((u >> 16) & 1)) >> 16);
}

// ================= node-type buckets (atomic-free, stable) =================
__global__ void bhist_k(const int* __restrict__ ntype, int N, int nblk, int* __restrict__ bcnt) {
    __shared__ int wc[4][NT];
    int b = blockIdx.x, tid = threadIdx.x, lane = tid & 63, w = tid >> 6;
    int i = b * 256 + tid;
    int t = (i < N) ? ntype[i] : -1;
#pragma unroll
    for (int r = 0; r < NT; ++r) {
        unsigned long long m = __ballot(t == r);
        if (lane == 0) wc[w][r] = __popcll(m);
    }
    __syncthreads();
    if (tid < NT) bcnt[tid * nblk + b] = wc[0][tid] + wc[1][tid] + wc[2][tid] + wc[3][tid];
}

__global__ void bscan_k(const int* __restrict__ bcnt, int* __restrict__ base,
                        int* __restrict__ off, int total, int nblk, int N) {
    __shared__ int s[1024];
    int t = threadIdx.x;
    int v = (t < total) ? bcnt[t] : 0;
    s[t] = v; __syncthreads();
    for (int o = 1; o < 1024; o <<= 1) {
        int u = (t >= o) ? s[t - o] : 0; __syncthreads();
        s[t] += u; __syncthreads();
    }
    if (t < total) base[t] = s[t] - v;
    if (t < NT) off[t] = s[t * nblk] - bcnt[t * nblk];
    if (t == NT) off[NT] = N;
}

__global__ void bscatter_k(const int* __restrict__ ntype, int N, int nblk,
                           const int* __restrict__ base, int* __restrict__ perm) {
    __shared__ int wc[4][NT];
    __shared__ int woff[4][NT];
    int b = blockIdx.x, tid = threadIdx.x, lane = tid & 63, w = tid >> 6;
    int i = b * 256 + tid;
    int t = (i < N) ? ntype[i] : -1;
    unsigned long long mlt = (1ULL << lane) - 1;
    int rank = 0;
#pragma unroll
    for (int r = 0; r < NT; ++r) {
        unsigned long long m = __ballot(t == r);
        if (lane == 0) wc[w][r] = __popcll(m);
        if (t == r) rank = __popcll(m & mlt);
    }
    __syncthreads();
    if (tid == 0) {
#pragma unroll
        for (int r = 0; r < NT; ++r) {
            int a = 0;
#pragma unroll
            for (int w0 = 0; w0 < 4; ++w0) { woff[w0][r] = a; a += wc[w0][r]; }
        }
    }
    __syncthreads();
    if (t >= 0) perm[base[t * nblk + b] + woff[w][t] + rank] = i;
}

// ================= edge counting sort by key = dst*ET + etype =================
__global__ void ehist_k(const int* __restrict__ dst, const int* __restrict__ etype, int E,
                        int* __restrict__ khist) {
    int i = blockIdx.x * 256 + threadIdx.x;
    if (i < E) atomicAdd(&khist[dst[i] * ET + etype[i]], 1);
}

__global__ void kscan1_k(const int* __restrict__ khist, int* __restrict__ kscan,
                         int* __restrict__ bsum, int KEYS) {
    __shared__ int s[256];
    int b = blockIdx.x, t = threadIdx.x, i = b * 256 + t;
    int v = (i < KEYS) ? khist[i] : 0;
    s[t] = v; __syncthreads();
    for (int o = 1; o < 256; o <<= 1) {
        int u = (t >= o) ? s[t - o] : 0; __syncthreads();
        s[t] += u; __syncthreads();
    }
    if (i < KEYS) kscan[i] = s[t] - v;
    if (t == 255) bsum[b] = s[t];
}

__global__ void kscan2_k(int* __restrict__ bsum, int NB) {
    __shared__ int s[1024];
    int t = threadIdx.x;
    int v = (t < NB) ? bsum[t] : 0;
    s[t] = v; __syncthreads();
    for (int o = 1; o < 1024; o <<= 1) {
        int u = (t >= o) ? s[t - o] : 0; __syncthreads();
        s[t] += u; __syncthreads();
    }
    if (t < NB) bsum[t] = s[t] - v;
}

__global__ void kscan3_k(int* __restrict__ kscan, const int* __restrict__ bsum, int KEYS) {
    int i = blockIdx.x * 256 + threadIdx.x;
    if (i < KEYS) kscan[i] += bsum[blockIdx.x];
}

__global__ void rowptr_k(const int* __restrict__ kscan, int* __restrict__ rowptr, int KEYS, int E) {
    int i = blockIdx.x * 256 + threadIdx.x;
    if (i < KEYS) rowptr[i] = kscan[i];
    if (i == KEYS) rowptr[KEYS] = E;
}

__global__ void escatter_k(const int* __restrict__ src, const int* __restrict__ dst,
                           const int* __restrict__ etype, int E,
                           int* __restrict__ kscan, int* __restrict__ epay) {
    int e = blockIdx.x * 256 + threadIdx.x;
    if (e < E) {
        int pos = atomicAdd(&kscan[dst[e] * ET + etype[e]], 1);
        epay[pos] = src[e];
    }
}

// ================= weight convert+transpose: W[t][k][c] f32 -> Wtb[t][c][k] bf16 ========
__global__ __launch_bounds__(256) void wconv_k(const float* __restrict__ W, u16* __restrict__ Wtb) {
    __shared__ u16 s[64][72];
    int k0 = blockIdx.x * 64, c0 = blockIdx.y * 64, t = blockIdx.z;
    const float* Wp = W + (size_t)t * CDIM * CDIM;
    int r = threadIdx.x >> 2, q = (threadIdx.x & 3) * 16;
#pragma unroll
    for (int m = 0; m < 16; m += 4) {
        float4 v = *(const float4*)(Wp + (size_t)(k0 + r) * CDIM + c0 + q + m);
        s[r][q + m + 0] = f2b(v.x); s[r][q + m + 1] = f2b(v.y);
        s[r][q + m + 2] = f2b(v.z); s[r][q + m + 3] = f2b(v.w);
    }
    __syncthreads();
    int c = threadIdx.x >> 2, kq = (threadIdx.x & 3) * 16;
    u16* op = Wtb + ((size_t)t * CDIM + c0 + c) * CDIM + k0 + kq;
#pragma unroll
    for (int m = 0; m < 16; m += 4) {
        ushort4 o;
        o.x = s[kq + m + 0][c]; o.y = s[kq + m + 1][c];
        o.z = s[kq + m + 2][c]; o.w = s[kq + m + 3][c];
        *(ushort4*)(op + m) = o;
    }
}

// ================= fp32 -> bf16 copy =================
__global__ void f2b_k(const float* __restrict__ in, u16* __restrict__ out, size_t n4) {
    size_t i = (size_t)blockIdx.x * 256 + threadIdx.x;
    if (i >= n4) return;
    float4 v = ((const float4*)in)[i];
    ushort4 o; o.x = f2b(v.x); o.y = f2b(v.y); o.z = f2b(v.z); o.w = f2b(v.w);
    ((ushort4*)out)[i] = o;
}

// ================= Rmsg -> bf16 [et][h][m][f] (transposed) =================
__global__ void rt2_k(const float* __restrict__ Rmsg, u16* __restrict__ rm_b) {
    int o = blockIdx.x * 256 + threadIdx.x;
    if (o >= ET * HD * DD * DD) return;
    int f = o & 31, m = (o >> 5) & 31, eh = o >> 10;
    rm_b[o] = f2b(Rmsg[(size_t)eh * 1024 + f * 32 + m]);
}

// ================= MFMA typed GEMM: out[perm[r]] = A[perm[r]] @ W[t] =================
template<int MODE>
__global__ __launch_bounds__(256) void gemm_mfma_k(
    const u16* __restrict__ A, const u16* __restrict__ Wtb, void* __restrict__ outv,
    const int* __restrict__ perm, const int* __restrict__ off, int N, int bpt,
    const float* __restrict__ x, const float* __restrict__ skip)
{
    __shared__ u16 As[64][40];
    __shared__ u16 Bs[64][40];
    __shared__ int ridx[64];

    int t = blockIdx.x / bpt, bi = blockIdx.x % bpt;
    int i0 = off[t] + bi * 64, iend = off[t + 1];
    if (i0 >= iend) return;
    int tid = threadIdx.x;
    int col0 = blockIdx.y * 64;

    if (tid < 64) ridx[tid] = (i0 + tid < iend) ? perm[i0 + tid] : -1;
    __syncthreads();

    int sr = tid >> 2, sq = (tid & 3) * 8;
    int ar = ridx[sr];
    const u16* asrc = A + (size_t)(ar >= 0 ? ar : 0) * CDIM + sq;
    const u16* bsrc = Wtb + ((size_t)t * CDIM + col0 + sr) * CDIM + sq;

    int lane = tid & 63, wid = tid >> 6;
    int wr = wid >> 1, wc = wid & 1;
    int l15 = lane & 15, lk = (lane >> 4) * 8;

    f32x4 acc00 = {0.f, 0.f, 0.f, 0.f}, acc01 = {0.f, 0.f, 0.f, 0.f};
    f32x4 acc10 = {0.f, 0.f, 0.f, 0.f}, acc11 = {0.f, 0.f, 0.f, 0.f};

    uint4 apre = make_uint4(0, 0, 0, 0), bpre;
    if (ar >= 0) apre = *(const uint4*)(asrc);
    bpre = *(const uint4*)(bsrc);

    for (int k0 = 0; k0 < CDIM; k0 += 32) {
        __syncthreads();
        *(uint4*)&As[sr][sq] = apre;
        *(uint4*)&Bs[sr][sq] = bpre;
        __syncthreads();

        if (k0 + 32 < CDIM) {
            if (ar >= 0) apre = *(const uint4*)(asrc + k0 + 32);
            bpre = *(const uint4*)(bsrc + k0 + 32);
        }

        s16x8 af0 = *(const s16x8*)&As[wr * 32 + l15][lk];
        s16x8 af1 = *(const s16x8*)&As[wr * 32 + 16 + l15][lk];
        s16x8 bf0 = *(const s16x8*)&Bs[wc * 32 + l15][lk];
        s16x8 bf1 = *(const s16x8*)&Bs[wc * 32 + 16 + l15][lk];

        acc00 = __builtin_amdgcn_mfma_f32_16x16x32_bf16(af0, bf0, acc00, 0, 0, 0);
        acc01 = __builtin_amdgcn_mfma_f32_16x16x32_bf16(af0, bf1, acc01, 0, 0, 0);
        acc10 = __builtin_amdgcn_mfma_f32_16x16x32_bf16(af1, bf0, acc10, 0, 0, 0);
        acc11 = __builtin_amdgcn_mfma_f32_16x16x32_bf16(af1, bf1, acc11, 0, 0, 0);
    }

    float alpha = 0.f, beta = 0.f;
    if (MODE == 1) {
        alpha = 1.f / (1.f + __expf(-skip[t]));
        beta = 1.f - alpha;
    }

    int rbase = wr * 32 + (lane >> 4) * 4;
#pragma unroll
    for (int mi = 0; mi < 2; ++mi) {
#pragma unroll
        for (int r = 0; r < 4; ++r) {
            int lrow = rbase + mi * 16 + r;
            int node = ridx[lrow];
            if (node < 0) continue;
            float v0 = (mi == 0) ? acc00[r] : acc10[r];
            float v1 = (mi == 0) ? acc01[r] : acc11[r];
            int c0i = col0 + wc * 32 + l15;
            if (MODE == 1) {
                float* out = (float*)outv;
                size_t b0 = (size_t)node * CDIM + c0i;
                out[b0]      = v0 * alpha + x[b0] * beta;
                out[b0 + 16] = v1 * alpha + x[b0 + 16] * beta;
            } else {
                u16* out = (u16*)outv;
                size_t b0 = (size_t)node * CDIM + c0i;
                out[b0]      = f2b(v0);
                out[b0 + 16] = f2b(v1);
            }
        }
    }
}

// ================= FAST: qw_all[n][et*256+h*32+m] = sum_f Ratt[et,h,m,f]*q[n,h*32+f] =====
__global__ __launch_bounds__(256) void relmm_qw_k(
    const u16* __restrict__ qb, const u16* __restrict__ ra_b,
    u16* __restrict__ qw_all, int N)
{
    int tid = threadIdx.x, lane = tid & 63, w = tid >> 6;
    int n0 = blockIdx.x * 64 + w * 16;
    int l15 = lane & 15, kg = lane >> 4;

    int arow = n0 + l15;
    bool arv = arow < N;
    const u16* qrow = qb + (size_t)(arv ? arow : 0) * CDIM + kg * 8;
    s16x8 afr[8];
#pragma unroll
    for (int h = 0; h < 8; ++h)
        afr[h] = arv ? *(const s16x8*)(qrow + h * 32) : (s16x8)0;

    int rb = kg * 4;
#pragma unroll
    for (int et = 0; et < ET; ++et) {
#pragma unroll
        for (int h = 0; h < 8; ++h) {
            const u16* bb = ra_b + (size_t)((et * 8 + h) * 32) * 32;
            s16x8 b0 = *(const s16x8*)(bb + l15 * 32 + kg * 8);
            s16x8 b1 = *(const s16x8*)(bb + (16 + l15) * 32 + kg * 8);
            f32x4 z = {0.f, 0.f, 0.f, 0.f};
            f32x4 d0 = __builtin_amdgcn_mfma_f32_16x16x32_bf16(afr[h], b0, z, 0, 0, 0);
            f32x4 d1 = __builtin_amdgcn_mfma_f32_16x16x32_bf16(afr[h], b1, z, 0, 0, 0);
#pragma unroll
            for (int r = 0; r < 4; ++r) {
                int rr = n0 + rb + r;
                if (rr < N) {
                    u16* op = qw_all + (size_t)rr * (ET * CDIM) + et * 256 + h * 32;
                    op[l15] = f2b(d0[r]);
                    op[16 + l15] = f2b(d1[r]);
                }
            }
        }
    }
}

// ================= FAST: edge gather -> Sv[d,et], den[d,h] (no matvecs) =================
__global__ __launch_bounds__(256) void gather_sv_k(
    const u16* __restrict__ kb, const u16* __restrict__ vb, const u16* __restrict__ qw_all,
    const float* __restrict__ pri, const int* __restrict__ rowptr, const int* __restrict__ epay,
    u16* __restrict__ sv_all, float* __restrict__ den, int N)
{
    int d = (blockIdx.x * 256 + threadIdx.x) >> 6;
    if (d >= N) return;
    int lane = threadIdx.x & 63, h = lane >> 3;
    const float rsD = 0.17677669529663687f;
    float dsum = 0.f;
    size_t rowb = (size_t)d * (ET * CDIM) + lane * 4;

#pragma unroll
    for (int et = 0; et < ET; ++et) {
        int key = d * ET + et;
        int p0 = rowptr[key], p1 = rowptr[key + 1];
        float Sv0 = 0.f, Sv1 = 0.f, Sv2 = 0.f, Sv3 = 0.f;
        if (p0 < p1) {
            float prif = pri[et * HD + h] * rsD;
            ushort4 qu = *(const ushort4*)(qw_all + rowb + et * 256);
            float q0 = b2f(qu.x), q1 = b2f(qu.y), q2 = b2f(qu.z), q3 = b2f(qu.w);
            for (int p = p0; p < p1; ++p) {
                int s = epay[p];
                ushort4 ku = *(const ushort4*)(kb + (size_t)s * CDIM + lane * 4);
                float t = b2f(ku.x) * q0 + b2f(ku.y) * q1 + b2f(ku.z) * q2 + b2f(ku.w) * q3;
                t += __shfl_xor(t, 1, 8);
                t += __shfl_xor(t, 2, 8);
                t += __shfl_xor(t, 4, 8);
                float ex = __expf(t * prif);
                ushort4 vu = *(const ushort4*)(vb + (size_t)s * CDIM + lane * 4);
                Sv0 += ex * b2f(vu.x); Sv1 += ex * b2f(vu.y);
                Sv2 += ex * b2f(vu.z); Sv3 += ex * b2f(vu.w);
                dsum += ex;
            }
        }
        ushort4 o;
        o.x = f2b(Sv0); o.y = f2b(Sv1); o.z = f2b(Sv2); o.w = f2b(Sv3);
        *(ushort4*)(sv_all + rowb + et * 256) = o;
    }
    if ((lane & 7) == 0) den[d * HD + h] = dsum;
}

// ================= FAST: O[n,h*32+m] = (sum_et sum_f Sv[n,et,h,f]*Rmsg[et,h,f,m])/den =====
__global__ __launch_bounds__(256) void relmm_o_k(
    const u16* __restrict__ sv_all, const u16* __restrict__ rm_b,
    const float* __restrict__ den, u16* __restrict__ hb, int N)
{
    __shared__ float inv_s[64][8];
    int tid = threadIdx.x, lane = tid & 63, w = tid >> 6;
    int nb = blockIdx.x * 64;

    for (int i = tid; i < 512; i += 256) {
        int r = i >> 3, hh = i & 7, rr = nb + r;
        float dv = (rr < N) ? den[rr * HD + hh] : 0.f;
        inv_s[r][hh] = dv > 0.f ? 1.f / dv : 0.f;
    }
    __syncthreads();

    int n0 = nb + w * 16;
    int l15 = lane & 15, kg = lane >> 4;
    int arow = n0 + l15;
    bool arv = arow < N;
    const u16* abase = sv_all + (size_t)(arv ? arow : 0) * (ET * CDIM) + kg * 8;

    f32x4 acc[8][2];
#pragma unroll
    for (int h = 0; h < 8; ++h) { acc[h][0] = (f32x4){0.f,0.f,0.f,0.f}; acc[h][1] = (f32x4){0.f,0.f,0.f,0.f}; }

#pragma unroll
    for (int et = 0; et < ET; ++et) {
#pragma unroll
        for (int h = 0; h < 8; ++h) {
            s16x8 af = arv ? *(const s16x8*)(abase + et * 256 + h * 32) : (s16x8)0;
            const u16* bb = rm_b + (size_t)((et * 8 + h) * 32) * 32;
            s16x8 b0 = *(const s16x8*)(bb + l15 * 32 + kg * 8);
            s16x8 b1 = *(const s16x8*)(bb + (16 + l15) * 32 + kg * 8);
            acc[h][0] = __builtin_amdgcn_mfma_f32_16x16x32_bf16(af, b0, acc[h][0], 0, 0, 0);
            acc[h][1] = __builtin_amdgcn_mfma_f32_16x16x32_bf16(af, b1, acc[h][1], 0, 0, 0);
        }
    }

    int rb = kg * 4;
#pragma unroll
    for (int h = 0; h < 8; ++h) {
#pragma unroll
        for (int r = 0; r < 4; ++r) {
            int rr = n0 + rb + r;
            if (rr < N) {
                float iv = inv_s[w * 16 + rb + r][h];
                u16* op = hb + (size_t)rr * CDIM + h * 32;
                op[l15] = f2b(acc[h][0][r] * iv);
                op[16 + l15] = f2b(acc[h][1][r] * iv);
            }
        }
    }
}

// ================= FALLBACK: R -> bf16 f-major + fused gather (round-6 path) ==========
__global__ void rt_k(const float* __restrict__ Ratt, const float* __restrict__ Rmsg,
                     u16* __restrict__ ra_t, u16* __restrict__ rm_t) {
    int o = blockIdx.x * 256 + threadIdx.x;
    if (o >= ET * DD * HD * DD) return;
    int m = o & 31, h2 = (o >> 5) & 7, f = (o >> 8) & 31, et = o >> 13;
    ra_t[o] = f2b(Ratt[(((et * 8 + h2) * 32 + m) * 32) + f]);
    rm_t[o] = f2b(Rmsg[(((et * 8 + h2) * 32 + f) * 32) + m]);
}

__global__ __launch_bounds__(256) void gather_all_k(
    const u16* __restrict__ kb, const u16* __restrict__ qb, const u16* __restrict__ vb,
    const u16* __restrict__ ra_t, const u16* __restrict__ rm_t, const float* __restrict__ pri,
    const int* __restrict__ rowptr, const int* __restrict__ epay,
    u16* __restrict__ hb, int N)
{
    __shared__ u16 Ra_s[DD * CDIM];
    __shared__ u16 Rm_s[DD * CDIM];

    int tid = threadIdx.x, lane = tid & 63, wv = tid >> 6;
    int h = lane >> 3;
    int dbase = blockIdx.x * 16 + wv * 4;

    float o[4][4] = {};
    float den[4] = {};
    const float rsD = 0.17677669529663687f;

    for (int et = 0; et < ET; ++et) {
        __syncthreads();
        {
            const uint4* rs = (const uint4*)(ra_t + (size_t)et * (DD * CDIM));
            const uint4* ms = (const uint4*)(rm_t + (size_t)et * (DD * CDIM));
            uint4* rl = (uint4*)Ra_s;
            uint4* ml = (uint4*)Rm_s;
#pragma unroll
            for (int i = 0; i < 4; ++i) {
                rl[i * 256 + tid] = rs[i * 256 + tid];
                ml[i * 256 + tid] = ms[i * 256 + tid];
            }
        }
        __syncthreads();
        float prif = pri[et * HD + h] * rsD;

#pragma unroll
        for (int s = 0; s < 4; ++s) {
            int d = dbase + s;
            if (d >= N) continue;
            int key = d * ET + et;
            int p0 = rowptr[key], p1 = rowptr[key + 1];
            if (p0 >= p1) continue;

            ushort4 qu = *(const ushort4*)(qb + (size_t)d * CDIM + lane * 4);
            float q0 = b2f(qu.x), q1 = b2f(qu.y), q2 = b2f(qu.z), q3 = b2f(qu.w);

            float qw0 = 0.f, qw1 = 0.f, qw2 = 0.f, qw3 = 0.f;
#pragma unroll 4
            for (int f = 0; f < DD; ++f) {
                float qs;
                switch (f & 3) {
                    case 0:  qs = q0; break;
                    case 1:  qs = q1; break;
                    case 2:  qs = q2; break;
                    default: qs = q3; break;
                }
                float qf = __shfl(qs, h * 8 + (f >> 2), 64);
                ushort4 rv = *(const ushort4*)&Ra_s[f * CDIM + lane * 4];
                qw0 += qf * b2f(rv.x); qw1 += qf * b2f(rv.y);
                qw2 += qf * b2f(rv.z); qw3 += qf * b2f(rv.w);
            }

            float Sv0 = 0.f, Sv1 = 0.f, Sv2 = 0.f, Sv3 = 0.f, ds = 0.f;
            for (int p = p0; p < p1; ++p) {
                int srcn = epay[p];
                ushort4 ku = *(const ushort4*)(kb + (size_t)srcn * CDIM + lane * 4);
                float t = b2f(ku.x) * qw0 + b2f(ku.y) * qw1 + b2f(ku.z) * qw2 + b2f(ku.w) * qw3;
                t += __shfl_xor(t, 1, 8);
                t += __shfl_xor(t, 2, 8);
                t += __shfl_xor(t, 4, 8);
                float ex = __expf(t * prif);
                ushort4 vu = *(const ushort4*)(vb + (size_t)srcn * CDIM + lane * 4);
                Sv0 += ex * b2f(vu.x); Sv1 += ex * b2f(vu.y);
                Sv2 += ex * b2f(vu.z); Sv3 += ex * b2f(vu.w);
                ds += ex;
            }
            den[s] += ds;

#pragma unroll 4
            for (int f = 0; f < DD; ++f) {
                int srcl = h * 8 + (f >> 2);
                float sf;
                switch (f & 3) {
                    case 0:  sf = __shfl(Sv0, srcl, 64); break;
                    case 1:  sf = __shfl(Sv1, srcl, 64); break;
                    case 2:  sf = __shfl(Sv2, srcl, 64); break;
                    default: sf = __shfl(Sv3, srcl, 64); break;
                }
                ushort4 rv = *(const ushort4*)&Rm_s[f * CDIM + lane * 4];
                o[s][0] += sf * b2f(rv.x); o[s][1] += sf * b2f(rv.y);
                o[s][2] += sf * b2f(rv.z); o[s][3] += sf * b2f(rv.w);
            }
        }
    }

#pragma unroll
    for (int s = 0; s < 4; ++s) {
        int d = dbase + s;
        if (d >= N) continue;
        float sc = den[s] > 0.f ? 1.f / den[s] : 0.f;
        ushort4 ov;
        ov.x = f2b(o[s][0] * sc); ov.y = f2b(o[s][1] * sc);
        ov.z = f2b(o[s][2] * sc); ov.w = f2b(o[s][3] * sc);
        *(ushort4*)(hb + (size_t)d * CDIM + lane * 4) = ov;
    }
}

// ================= launch =================
extern "C" void kernel_launch(void* const* d_in, const int* in_sizes, int n_in,
                              void* d_out, int out_size, void* d_ws, size_t ws_size,
                              hipStream_t stream) {
    const float* x    = (const float*)d_in[0];
    const float* Wk   = (const float*)d_in[1];
    const float* Wq   = (const float*)d_in[2];
    const float* Wv   = (const float*)d_in[3];
    const float* Ratt = (const float*)d_in[4];
    const float* Rmsg = (const float*)d_in[5];
    const float* pri  = (const float*)d_in[6];
    const float* Wa   = (const float*)d_in[7];
    const float* skip = (const float*)d_in[8];
    const int* src   = (const int*)d_in[9];
    const int* dst   = (const int*)d_in[10];
    const int* etype = (const int*)d_in[11];
    const int* ntype = (const int*)d_in[12];

    int N = in_sizes[12];
    int E = in_sizes[9];
    const size_t NC = (size_t)N * CDIM;
    const int KEYS = N * ET;
    const int NB = (KEYS + 255) / 256;
    const int nblk = (N + 255) / 256;
    const size_t WTE = (size_t)NT * CDIM * CDIM;
    const size_t RTE = (size_t)ET * DD * HD * DD;   // 40960
    const size_t intcnt = (size_t)KEYS * 2 + 1024 + (KEYS + 1) + N + E + 2 * (size_t)NT * nblk + 8;

    // ---- fast layout bytes ----
    size_t fast_bytes = (4 * NC + 10 * NC) * sizeof(u16) + (size_t)N * HD * sizeof(float)
                      + (4 * WTE + 2 * RTE) * sizeof(u16) + intcnt * sizeof(int) + 1024;
    bool fast = ws_size >= fast_bytes;

    int bpt = (N + 63) / 64;
    dim3 gg(NT * bpt, CDIM / 64);
    dim3 wg(4, 4, NT);
    size_t n4 = NC / 4;

    if (fast) {
        u16* xb     = (u16*)d_ws;                    // NC (reused as hb)
        u16* kb     = xb + NC;
        u16* qb     = kb + NC;
        u16* vb     = qb + NC;
        u16* qw_all = vb + NC;                       // 5*NC
        u16* sv_all = qw_all + 5 * NC;               // 5*NC
        float* den  = (float*)(sv_all + 5 * NC);     // N*HD
        u16* wtb    = (u16*)(den + (size_t)N * HD);  // 4*WTE
        u16* ra_b   = wtb + 4 * WTE;                 // RTE
        u16* rm_b   = ra_b + RTE;                    // RTE
        int* khist  = (int*)(rm_b + RTE);            // KEYS (zeroed)
        int* kscan  = khist + KEYS;
        int* bsum   = kscan + KEYS;
        int* rowptr = bsum + 1024;
        int* perm   = rowptr + KEYS + 1;
        int* epay   = perm + N;
        int* bcnt   = epay + E;
        int* base   = bcnt + NT * nblk;
        int* off    = base + NT * nblk;
        u16* hb = xb;

        hipMemsetAsync(khist, 0, (size_t)KEYS * sizeof(int), stream);

        bhist_k<<<nblk, 256, 0, stream>>>(ntype, N, nblk, bcnt);
        bscan_k<<<1, 1024, 0, stream>>>(bcnt, base, off, NT * nblk, nblk, N);
        bscatter_k<<<nblk, 256, 0, stream>>>(ntype, N, nblk, base, perm);

        ehist_k<<<(E + 255) / 256, 256, 0, stream>>>(dst, etype, E, khist);
        kscan1_k<<<NB, 256, 0, stream>>>(khist, kscan, bsum, KEYS);
        kscan2_k<<<1, 1024, 0, stream>>>(bsum, NB);
        kscan3_k<<<NB, 256, 0, stream>>>(kscan, bsum, KEYS);
        rowptr_k<<<(KEYS + 256) / 256, 256, 0, stream>>>(kscan, rowptr, KEYS, E);
        escatter_k<<<(E + 255) / 256, 256, 0, stream>>>(src, dst, etype, E, kscan, epay);

        wconv_k<<<wg, 256, 0, stream>>>(Wk, wtb + 0 * WTE);
        wconv_k<<<wg, 256, 0, stream>>>(Wq, wtb + 1 * WTE);
        wconv_k<<<wg, 256, 0, stream>>>(Wv, wtb + 2 * WTE);
        wconv_k<<<wg, 256, 0, stream>>>(Wa, wtb + 3 * WTE);
        f2b_k<<<(int)((n4 + 255) / 256), 256, 0, stream>>>(x, xb, n4);
        f2b_k<<<(int)((RTE / 4 + 255) / 256), 256, 0, stream>>>(Ratt, ra_b, RTE / 4);
        rt2_k<<<(int)((RTE + 255) / 256), 256, 0, stream>>>(Rmsg, rm_b);

        gemm_mfma_k<0><<<gg, 256, 0, stream>>>(xb, wtb + 0 * WTE, kb, perm, off, N, bpt, nullptr, nullptr);
        gemm_mfma_k<0><<<gg, 256, 0, stream>>>(xb, wtb + 1 * WTE, qb, perm, off, N, bpt, nullptr, nullptr);
        gemm_mfma_k<0><<<gg, 256, 0, stream>>>(xb, wtb + 2 * WTE, vb, perm, off, N, bpt, nullptr, nullptr);

        relmm_qw_k<<<(N + 63) / 64, 256, 0, stream>>>(qb, ra_b, qw_all, N);
        gather_sv_k<<<(N * 64 + 255) / 256, 256, 0, stream>>>(kb, vb, qw_all, pri, rowptr, epay,
                                                              sv_all, den, N);
        relmm_o_k<<<(N + 63) / 64, 256, 0, stream>>>(sv_all, rm_b, den, hb, N);

        gemm_mfma_k<1><<<gg, 256, 0, stream>>>(hb, wtb + 3 * WTE, (float*)d_out, perm, off, N, bpt,
                                               x, skip);
    } else {
        u16* kb   = (u16*)d_ws;
        u16* qb   = kb + NC;
        u16* vb   = qb + NC;
        u16* xb   = vb + NC;
        u16* wtb  = xb + NC;
        u16* ra_t = wtb + 4 * WTE;
        u16* rm_t = ra_t + RTE;
        int* khist  = (int*)(rm_t + RTE);
        int* kscan  = khist + KEYS;
        int* bsum   = kscan + KEYS;
        int* rowptr = bsum + 1024;
        int* perm   = rowptr + KEYS + 1;
        int* epay   = perm + N;
        int* bcnt   = epay + E;
        int* base   = bcnt + NT * nblk;
        int* off    = base + NT * nblk;
        u16* hb = xb;

        hipMemsetAsync(khist, 0, (size_t)KEYS * sizeof(int), stream);

        bhist_k<<<nblk, 256, 0, stream>>>(ntype, N, nblk, bcnt);
        bscan_k<<<1, 1024, 0, stream>>>(bcnt, base, off, NT * nblk, nblk, N);
        bscatter_k<<<nblk, 256, 0, stream>>>(ntype, N, nblk, base, perm);

        ehist_k<<<(E + 255) / 256, 256, 0, stream>>>(dst, etype, E, khist);
        kscan1_k<<<NB, 256, 0, stream>>>(khist, kscan, bsum, KEYS);
        kscan2_k<<<1, 1024, 0, stream>>>(bsum, NB);
        kscan3_k<<<NB, 256, 0, stream>>>(kscan, bsum, KEYS);
        rowptr_k<<<(KEYS + 256) / 256, 256, 0, stream>>>(kscan, rowptr, KEYS, E);
        escatter_k<<<(E + 255) / 256, 256, 0, stream>>>(src, dst, etype, E, kscan, epay);

        wconv_k<<<wg, 256, 0, stream>>>(Wk, wtb + 0 * WTE);
        wconv_k<<<wg, 256, 0, stream>>>(Wq, wtb + 1 * WTE);
        wconv_k<<<wg, 256, 0, stream>>>(Wv, wtb + 2 * WTE);
        wconv_k<<<wg, 256, 0, stream>>>(Wa, wtb + 3 * WTE);
        rt_k<<<(int)((RTE + 255) / 256), 256, 0, stream>>>(Ratt, Rmsg, ra_t, rm_t);
        f2b_k<<<(int)((n4 + 255) / 256), 256, 0, stream>>>(x, xb, n4);

        gemm_mfma_k<0><<<gg, 256, 0, stream>>>(xb, wtb + 0 * WTE, kb, perm, off, N, bpt, nullptr, nullptr);
        gemm_mfma_k<0><<<gg, 256, 0, stream>>>(xb, wtb + 1 * WTE, qb, perm, off, N, bpt, nullptr, nullptr);
        gemm_mfma_k<0><<<gg, 256, 0, stream>>>(xb, wtb + 2 * WTE, vb, perm, off, N, bpt, nullptr, nullptr);

        gather_all_k<<<(N + 15) / 16, 256, 0, stream>>>(kb, qb, vb, ra_t, rm_t, pri,
                                                        rowptr, epay, hb, N);

        gemm_mfma_k<1><<<gg, 256, 0, stream>>>(hb, wtb + 3 * WTE, (float*)d_out, perm, off, N, bpt,
                                               x, skip);
    }
}